// Round 6
// baseline (254.013 us; speedup 1.0000x reference)
//
#include <hip/hip_runtime.h>
#include <math.h>

#define N 8192
#define C 128
#define NC 256
#define KNN 5

#define TP 128                        // tile size
#define NTILE (N / TP)                // 64
#define NPAIR (NTILE * (NTILE + 1) / 2)   // 2080
#define CH 16                         // channels per staging chunk (f64 path)
#define PJ 130                        // LDS pitch over row-dim (f64 path)
#define SQRT_C 11.313708498984761     // sqrt(128)

typedef double d4 __attribute__((ext_vector_type(4)));
using bf16x8 = __attribute__((ext_vector_type(8))) __bf16;
using f32x4  = __attribute__((ext_vector_type(4))) float;

static __device__ __forceinline__ unsigned rotl32(unsigned x, unsigned r) {
    return (x << r) | (x >> (32u - r));
}

// order-preserving double -> uint64 map (ascending)
static __device__ __forceinline__ unsigned long long dmap(double x) {
    long long b = __double_as_longlong(x);
    unsigned long long u = (unsigned long long)b;
    return (b >= 0) ? (u | 0x8000000000000000ull) : ~u;
}
static __device__ __forceinline__ double dunmap(unsigned long long u) {
    if (u & 0x8000000000000000ull) return __longlong_as_double((long long)(u ^ 0x8000000000000000ull));
    return __longlong_as_double((long long)(~u));
}

// async global->LDS, 16B per lane (dest = wave-uniform base + lane*16)
static __device__ __forceinline__ void gl_lds16(const void* g, void* l) {
    __builtin_amdgcn_global_load_lds(
        (const __attribute__((address_space(1))) void*)g,
        (__attribute__((address_space(3))) void*)l,
        16, 0, 0);
}

// ---------------------------------------------------------------------------
// Branchless sorted top-5 (ascending), f64 (fallback path).  (proven R13)
static __device__ __forceinline__ void ins5s(double (&m)[KNN], double v) {
    m[4] = fmin(m[4], fmax(m[3], v));
    m[3] = fmin(m[3], fmax(m[2], v));
    m[2] = fmin(m[2], fmax(m[1], v));
    m[1] = fmin(m[1], fmax(m[0], v));
    m[0] = fmin(m[0], v);
}
static __device__ __forceinline__ void sort5(double (&m)[KNN]) {
    double lo, hi;
#define CE(i, j) lo = fmin(m[i], m[j]); hi = fmax(m[i], m[j]); m[i] = lo; m[j] = hi;
    CE(0,1) CE(3,4) CE(2,4) CE(2,3) CE(0,3) CE(0,2) CE(1,4) CE(1,3) CE(1,2)
#undef CE
}
static __device__ __forceinline__ void bfly5s(double (&m)[KNN], int mask) {
    double pv[KNN];
    #pragma unroll
    for (int k = 0; k < KNN; k++) pv[k] = __shfl_xor(m[4 - k], mask, 64);
    #pragma unroll
    for (int k = 0; k < KNN; k++) m[k] = fmin(m[k], pv[k]);
    sort5(m);
}

// ---------------------------------------------------------------------------
// f32 versions (bf16 path).  Pure selection networks on f32 values: exact.
static __device__ __forceinline__ void ins5f(float (&m)[KNN], float v) {
    m[4] = fminf(m[4], fmaxf(m[3], v));
    m[3] = fminf(m[3], fmaxf(m[2], v));
    m[2] = fminf(m[2], fmaxf(m[1], v));
    m[1] = fminf(m[1], fmaxf(m[0], v));
    m[0] = fminf(m[0], v);
}
static __device__ __forceinline__ void sort5f(float (&m)[KNN]) {
    float lo, hi;
#define CE(i, j) lo = fminf(m[i], m[j]); hi = fmaxf(m[i], m[j]); m[i] = lo; m[j] = hi;
    CE(0,1) CE(3,4) CE(2,4) CE(2,3) CE(0,3) CE(0,2) CE(1,4) CE(1,3) CE(1,2)
#undef CE
}
static __device__ __forceinline__ void bfly5f(float (&m)[KNN], int mask) {
    float pv[KNN];
    #pragma unroll
    for (int k = 0; k < KNN; k++) pv[k] = __shfl_xor(m[4 - k], mask, 64);
    #pragma unroll
    for (int k = 0; k < KNN; k++) m[k] = fminf(m[k], pv[k]);
    sort5f(m);
}
static __device__ __forceinline__ void merge5f(float (&m)[KNN], const float* l) {
    #pragma unroll
    for (int k = 0; k < KNN; k++) m[k] = fminf(m[k], l[4 - k]);
    sort5f(m);
}

// ---------------------------------------------------------------------------
// f64 MFMA D-layout probe (proven R15) — fallback path only.
static __device__ __forceinline__ void probe_rows(int t, int r, int (&irow)[4]) {
    d4 pd = (d4){0.0, 0.0, 0.0, 0.0};
    pd = __builtin_amdgcn_mfma_f64_16x16x4f64((double)r, (r == 0) ? 1.0 : 0.0,
                                              pd, 0, 0, 0);
    #pragma unroll
    for (int j = 0; j < 4; j++) {
        double rv = __shfl(pd[j], t & 48, 64);   // group root lane 16*g
        irow[j] = (int)(rv * 0.25);
    }
}

// ---------------------------------------------------------------------------
// Fused setup: sq + gmin/d2max init + threefry noise + bf16x3 plane split.
// ---------------------------------------------------------------------------
__global__ void setup_kernel(const float* __restrict__ X,
                             double* __restrict__ sq,
                             unsigned long long* __restrict__ d2max,
                             unsigned long long* __restrict__ gmin,
                             float* __restrict__ noise,
                             __bf16* __restrict__ X1,
                             __bf16* __restrict__ X2,
                             __bf16* __restrict__ X3)
{
    int gid = blockIdx.x * blockDim.x + threadIdx.x;
    int wave = gid >> 6;
    int lane = threadIdx.x & 63;

    if (wave < N) {
        float f0 = X[wave * C + lane];
        float f1 = X[wave * C + 64 + lane];
        double v0 = (double)f0, v1 = (double)f1;
        double s = v0 * v0 + v1 * v1;
        #pragma unroll
        for (int off = 32; off > 0; off >>= 1) s += __shfl_down(s, off, 64);
        if (lane == 0) sq[wave] = s;

        // split f32 -> 3 bf16 planes (RNE at each stage)
        __bf16 a0 = (__bf16)f0; float r0 = f0 - (float)a0;
        __bf16 b0 = (__bf16)r0; r0 -= (float)b0;
        __bf16 c0 = (__bf16)r0;
        __bf16 a1 = (__bf16)f1; float r1 = f1 - (float)a1;
        __bf16 b1 = (__bf16)r1; r1 -= (float)b1;
        __bf16 c1 = (__bf16)r1;
        X1[wave * C + lane] = a0;  X1[wave * C + 64 + lane] = a1;
        X2[wave * C + lane] = b0;  X2[wave * C + 64 + lane] = b1;
        X3[wave * C + lane] = c0;  X3[wave * C + 64 + lane] = c1;
    }
    if (gid < N) gmin[gid] = 0xFFFFFFFFFFFFFFFFull;
    if (gid == 0) *d2max = 0ull;
    if (gid < N / 2) {
        int j = gid;
        const unsigned ks0 = 0u, ks1 = 1u;
        const unsigned ks2 = 0x1BD11BDAu ^ ks0 ^ ks1;
        unsigned x0 = (unsigned)j + ks0;
        unsigned x1 = (unsigned)(j + N / 2) + ks1;
        const unsigned rotA[4] = {13u, 15u, 26u, 6u};
        const unsigned rotB[4] = {17u, 29u, 16u, 24u};
        #pragma unroll
        for (int q = 0; q < 4; q++) { x0 += x1; x1 = rotl32(x1, rotA[q]); x1 ^= x0; }
        x0 += ks1; x1 += ks2 + 1u;
        #pragma unroll
        for (int q = 0; q < 4; q++) { x0 += x1; x1 = rotl32(x1, rotB[q]); x1 ^= x0; }
        x0 += ks2; x1 += ks0 + 2u;
        #pragma unroll
        for (int q = 0; q < 4; q++) { x0 += x1; x1 = rotl32(x1, rotA[q]); x1 ^= x0; }
        x0 += ks0; x1 += ks1 + 3u;
        #pragma unroll
        for (int q = 0; q < 4; q++) { x0 += x1; x1 = rotl32(x1, rotB[q]); x1 ^= x0; }
        x0 += ks1; x1 += ks2 + 4u;
        #pragma unroll
        for (int q = 0; q < 4; q++) { x0 += x1; x1 = rotl32(x1, rotA[q]); x1 ^= x0; }
        x0 += ks2; x1 += ks0 + 5u;
        unsigned b0u = (x0 >> 9) | 0x3f800000u;
        unsigned b1u = (x1 >> 9) | 0x3f800000u;
        noise[j]         = __uint_as_float(b0u) - 1.0f;
        noise[j + N / 2] = __uint_as_float(b1u) - 1.0f;
    }
}

// p = bj*(bj+1)/2 + bi, bi <= bj
static __device__ __forceinline__ void pair_decode(int p, int& bi, int& bj) {
    int b = (int)((sqrt(8.0 * (double)p + 1.0) - 1.0) * 0.5);
    while ((b + 1) * (b + 2) / 2 <= p) b++;
    while (b * (b + 1) / 2 > p) b--;
    bj = b;
    bi = p - b * (b + 1) / 2;
}

// ---------------------------------------------------------------------------
// symA_bf16: bf16x3 split-GEMM via v_mfma_f32_16x16x32_bf16.
//  - B-operand: global_load_lds (16B/lane) into linear LDS [pl][kg][point],
//    double-buffered (2 x 24 KB).  Zero staging VGPRs.
//  - A-operand: per-lane direct 16B global loads, PIPELINED one chunk ahead
//    (latency drains into the barrier wait, not the MFMA block).
//  - 3 blocks/CU co-resident (LDS 3x48K = 144K <= 160K; VGPR ~120 <= 128).
//  - acc bit-identical to R5 (same values, same MFMA order).
// ---------------------------------------------------------------------------
__launch_bounds__(256, 3)
__global__ void symA_bf16_kernel(const __bf16* __restrict__ X1,
                                 const __bf16* __restrict__ X2,
                                 const __bf16* __restrict__ X3,
                                 const double* __restrict__ sq,
                                 float* __restrict__ rec_dir,
                                 float* __restrict__ rec_tr,
                                 float* __restrict__ rec_d2,
                                 unsigned long long* __restrict__ d2max_p)
{
    __shared__ __align__(16) float4 Sb[2 * 1536];   // 49,152 B (double-buffered B)

    const int t = threadIdx.x;
    const int r = t & 15;
    const int g = (t >> 4) & 3;
    const int w = t >> 6;
    const int l = t & 63;
    const int w32 = w * 32;
    int bi, bj;
    pair_decode(blockIdx.x, bi, bj);
    const int i0 = bi * TP, j0 = bj * TP;

    f32x4 acc[2][8];
    #pragma unroll
    for (int mt = 0; mt < 2; mt++)
        #pragma unroll
        for (int nt = 0; nt < 8; nt++) acc[mt][nt] = (f32x4){0.f, 0.f, 0.f, 0.f};

    const int kgw = (w >> 1);
    const int p0  = (w & 1) * 64;

    // A row base offsets (lane-invariant part hoisted)
    const size_t arow0 = (size_t)(i0 + w32 + r) * C + g * 8;
    const size_t arow1 = (size_t)(i0 + w32 + 16 + r) * C + g * 8;

#define STAGE_B(ck, buf)                                                       \
    {                                                                          \
        _Pragma("unroll")                                                      \
        for (int pl = 0; pl < 3; pl++) {                                       \
            const __bf16* P = (pl == 0) ? X1 : ((pl == 1) ? X2 : X3);          \
            _Pragma("unroll")                                                  \
            for (int h = 0; h < 2; h++) {                                      \
                int kg = h * 2 + kgw;                                          \
                const __bf16* gp = P + (size_t)(j0 + p0 + l) * C               \
                                     + (ck) * 32 + kg * 8;                     \
                float4* lp = Sb + (buf) * 1536 + pl * 512 + h * 256 + w * 64;  \
                gl_lds16((const void*)gp, (void*)lp);                          \
            }                                                                  \
        }                                                                      \
    }

#define LOAD_A(ck, areg)                                                       \
    {                                                                          \
        areg[0][0] = *(const bf16x8*)(X1 + arow0 + (ck) * 32);                 \
        areg[0][1] = *(const bf16x8*)(X2 + arow0 + (ck) * 32);                 \
        areg[0][2] = *(const bf16x8*)(X3 + arow0 + (ck) * 32);                 \
        areg[1][0] = *(const bf16x8*)(X1 + arow1 + (ck) * 32);                 \
        areg[1][1] = *(const bf16x8*)(X2 + arow1 + (ck) * 32);                 \
        areg[1][2] = *(const bf16x8*)(X3 + arow1 + (ck) * 32);                 \
    }

    bf16x8 areg[2][2][3];   // [parity][mt][pl] — static-indexed after unroll

    // prologue: A(0) + stage B(0) into buffer 0
    LOAD_A(0, areg[0])
    STAGE_B(0, 0)
    __syncthreads();

    #pragma unroll
    for (int ck = 0; ck < 4; ck++) {
        const int cur = ck & 1;
        if (ck < 3) {
            STAGE_B(ck + 1, cur ^ 1)      // async global->LDS (next B)
            LOAD_A(ck + 1, areg[cur ^ 1]) // global->VGPR (next A, drains at barrier)
        }
        const bf16x8* SB = (const bf16x8*)Sb + (size_t)cur * 1536;
        #pragma unroll
        for (int nt = 0; nt < 8; nt++) {
            bf16x8 b0 = SB[0 * 512 + g * 128 + nt * 16 + r];
            bf16x8 b1 = SB[1 * 512 + g * 128 + nt * 16 + r];
            bf16x8 b2 = SB[2 * 512 + g * 128 + nt * 16 + r];
            #pragma unroll
            for (int mt = 0; mt < 2; mt++) {
                f32x4 c = acc[mt][nt];
                c = __builtin_amdgcn_mfma_f32_16x16x32_bf16(areg[cur][mt][0], b0, c, 0, 0, 0);
                c = __builtin_amdgcn_mfma_f32_16x16x32_bf16(areg[cur][mt][0], b1, c, 0, 0, 0);
                c = __builtin_amdgcn_mfma_f32_16x16x32_bf16(areg[cur][mt][1], b0, c, 0, 0, 0);
                c = __builtin_amdgcn_mfma_f32_16x16x32_bf16(areg[cur][mt][0], b2, c, 0, 0, 0);
                c = __builtin_amdgcn_mfma_f32_16x16x32_bf16(areg[cur][mt][2], b0, c, 0, 0, 0);
                c = __builtin_amdgcn_mfma_f32_16x16x32_bf16(areg[cur][mt][1], b1, c, 0, 0, 0);
                acc[mt][nt] = c;
            }
        }
        __syncthreads();   // drains vmcnt -> next buffer + next A ready
    }
#undef STAGE_B
#undef LOAD_A

    // d2 in place (f32) + wave max -> global atomic
    double sqa[2][4], sqj[8];
    #pragma unroll
    for (int mt = 0; mt < 2; mt++)
        #pragma unroll
        for (int j = 0; j < 4; j++) sqa[mt][j] = sq[i0 + w32 + mt * 16 + g * 4 + j];
    #pragma unroll
    for (int nt = 0; nt < 8; nt++) sqj[nt] = sq[j0 + nt * 16 + r];
    double rmax = 0.0;
    #pragma unroll
    for (int mt = 0; mt < 2; mt++)
        #pragma unroll
        for (int nt = 0; nt < 8; nt++)
            #pragma unroll
            for (int j = 0; j < 4; j++) {
                double v = sqa[mt][j] + sqj[nt] - 2.0 * (double)acc[mt][nt][j];
                acc[mt][nt][j] = (float)v;
                rmax = fmax(rmax, v);
            }
    #pragma unroll
    for (int off = 32; off > 0; off >>= 1) rmax = fmax(rmax, __shfl_down(rmax, off, 64));
    if ((t & 63) == 0)
        atomicMax(d2max_p, (unsigned long long)__double_as_longlong(fmax(rmax, 0.0)));

    // ---- PERMUTED d2 store: lane's float4 at [(mt*8+nt)*256 + t]  (coalesced)
    {
        float4* outp = (float4*)(rec_d2 + (size_t)blockIdx.x * (TP * TP));
        #pragma unroll
        for (int mt = 0; mt < 2; mt++)
            #pragma unroll
            for (int nt = 0; nt < 8; nt++) {
                f32x4 v = acc[mt][nt];
                outp[(mt * 8 + nt) * 256 + t] = (float4){v[0], v[1], v[2], v[3]};
            }
    }

    // ---- rows: lane scans 8 nt values; bfly over r lanes; r==0 writes. (f32)
    #pragma unroll
    for (int mt = 0; mt < 2; mt++)
        #pragma unroll
        for (int j = 0; j < 4; j++) {
            float m5[KNN];
            #pragma unroll
            for (int k = 0; k < KNN; k++) m5[k] = 3.0e38f;
            #pragma unroll
            for (int nt = 0; nt < 8; nt++) ins5f(m5, acc[mt][nt][j]);
            bfly5f(m5, 1); bfly5f(m5, 2); bfly5f(m5, 4); bfly5f(m5, 8);
            if (r == 0) {
                int row = w32 + mt * 16 + g * 4 + j;
                float* outp = &rec_dir[(size_t)blockIdx.x * (TP * KNN) + row * KNN];
                #pragma unroll
                for (int k = 0; k < KNN; k++) outp[k] = m5[k];
            }
        }

    // ---- cols (off-diagonal): scan 8 (mt,j); bfly over g (16,32); LDS merge
    if (bi != bj) {
        float* M = (float*)Sb;   // [col][21] : 4 wave-partials x 5
        #pragma unroll
        for (int nt = 0; nt < 8; nt++) {
            float m5[KNN];
            #pragma unroll
            for (int k = 0; k < KNN; k++) m5[k] = 3.0e38f;
            #pragma unroll
            for (int mt = 0; mt < 2; mt++)
                #pragma unroll
                for (int j = 0; j < 4; j++) ins5f(m5, acc[mt][nt][j]);
            bfly5f(m5, 16); bfly5f(m5, 32);
            if (g == 0) {
                int col = nt * 16 + r;
                #pragma unroll
                for (int k = 0; k < KNN; k++) M[col * 21 + w * 5 + k] = m5[k];
            }
        }
        __syncthreads();
        if (t < 128) {
            float m5[KNN];
            #pragma unroll
            for (int k = 0; k < KNN; k++) m5[k] = M[t * 21 + k];
            merge5f(m5, &M[t * 21 + 5]);
            merge5f(m5, &M[t * 21 + 10]);
            merge5f(m5, &M[t * 21 + 15]);
            float* outp = &rec_tr[(size_t)blockIdx.x * (TP * KNN) + t * KNN];
            #pragma unroll
            for (int k = 0; k < KNN; k++) outp[k] = m5[k];
        }
    }
}

// ---------------------------------------------------------------------------
// f64 MFMA GEMM body (proven) — fallback path only.
// ---------------------------------------------------------------------------
#define MFMA_GEMM_BODY(acc, As, Bs, X4, i0, j0, t, r, g, w32)                  \
    {                                                                          \
        float4 pa[2], pb[2];                                                   \
        _Pragma("unroll")                                                      \
        for (int q = 0; q < 2; q++) {                                          \
            int flat = t + 256 * q;                                            \
            int row = flat >> 2, c4 = flat & 3;                                \
            pa[q] = X4[(size_t)(i0 + row) * 32 + c4];                          \
            pb[q] = X4[(size_t)(j0 + row) * 32 + c4];                          \
        }                                                                      \
        for (int ck = 0; ck < 8; ck++) {                                       \
            _Pragma("unroll")                                                  \
            for (int q = 0; q < 2; q++) {                                      \
                int flat = t + 256 * q;                                        \
                int row = flat >> 2, c4 = flat & 3;                            \
                As[(4 * c4 + 0) * PJ + row] = (double)pa[q].x;                 \
                As[(4 * c4 + 1) * PJ + row] = (double)pa[q].y;                 \
                As[(4 * c4 + 2) * PJ + row] = (double)pa[q].z;                 \
                As[(4 * c4 + 3) * PJ + row] = (double)pa[q].w;                 \
                Bs[(4 * c4 + 0) * PJ + row] = (double)pb[q].x;                 \
                Bs[(4 * c4 + 1) * PJ + row] = (double)pb[q].y;                 \
                Bs[(4 * c4 + 2) * PJ + row] = (double)pb[q].z;                 \
                Bs[(4 * c4 + 3) * PJ + row] = (double)pb[q].w;                 \
            }                                                                  \
            __syncthreads();                                                   \
            if (ck < 7) {                                                      \
                _Pragma("unroll")                                              \
                for (int q = 0; q < 2; q++) {                                  \
                    int flat = t + 256 * q;                                    \
                    int row = flat >> 2, c4 = flat & 3;                        \
                    pa[q] = X4[(size_t)(i0 + row) * 32 + (ck + 1) * 4 + c4];   \
                    pb[q] = X4[(size_t)(j0 + row) * 32 + (ck + 1) * 4 + c4];   \
                }                                                              \
            }                                                                  \
            _Pragma("unroll")                                                  \
            for (int ks = 0; ks < 4; ks++) {                                   \
                int cc = 4 * ks + g;                                           \
                double a0 = As[cc * PJ + w32 + r];                             \
                double a1 = As[cc * PJ + w32 + 16 + r];                        \
                double bv[8];                                                  \
                _Pragma("unroll")                                              \
                for (int nt = 0; nt < 8; nt++) bv[nt] = Bs[cc * PJ + nt * 16 + r]; \
                _Pragma("unroll")                                              \
                for (int nt = 0; nt < 8; nt++)                                 \
                    acc[0][nt] = __builtin_amdgcn_mfma_f64_16x16x4f64(a0, bv[nt], acc[0][nt], 0, 0, 0); \
                _Pragma("unroll")                                              \
                for (int nt = 0; nt < 8; nt++)                                 \
                    acc[1][nt] = __builtin_amdgcn_mfma_f64_16x16x4f64(a1, bv[nt], acc[1][nt], 0, 0, 0); \
            }                                                                  \
            __syncthreads();                                                   \
        }                                                                      \
    }

// ---------------------------------------------------------------------------
// symA_f64 (fallback): proven f64 GEMM + top-5 epilogue, float records.
// ---------------------------------------------------------------------------
__launch_bounds__(256, 2)
__global__ void symA_f64_kernel(const float* __restrict__ X,
                                const double* __restrict__ sq,
                                float* __restrict__ rec_dir,
                                float* __restrict__ rec_tr,
                                unsigned long long* __restrict__ d2max_p)
{
    __shared__ __align__(16) double S[2 * CH * PJ];
    double* As = S;
    double* Bs = S + CH * PJ;

    const int t = threadIdx.x;
    const int r = t & 15;
    const int g = (t >> 4) & 3;
    const int w = t >> 6;
    const int w32 = w * 32;
    int bi, bj;
    pair_decode(blockIdx.x, bi, bj);
    const int i0 = bi * TP, j0 = bj * TP;
    const float4* X4 = (const float4*)X;

    int irow[4];
    probe_rows(t, r, irow);

    d4 acc[2][8];
    #pragma unroll
    for (int mt = 0; mt < 2; mt++)
        #pragma unroll
        for (int nt = 0; nt < 8; nt++) acc[mt][nt] = (d4){0.0, 0.0, 0.0, 0.0};

    MFMA_GEMM_BODY(acc, As, Bs, X4, i0, j0, t, r, g, w32)

    double sqa[2][4], sqj[8];
    #pragma unroll
    for (int mt = 0; mt < 2; mt++)
        #pragma unroll
        for (int j = 0; j < 4; j++) sqa[mt][j] = sq[i0 + w32 + mt * 16 + irow[j]];
    #pragma unroll
    for (int nt = 0; nt < 8; nt++) sqj[nt] = sq[j0 + nt * 16 + r];
    double rmax = 0.0;
    #pragma unroll
    for (int mt = 0; mt < 2; mt++)
        #pragma unroll
        for (int nt = 0; nt < 8; nt++)
            #pragma unroll
            for (int j = 0; j < 4; j++) {
                double v = sqa[mt][j] + sqj[nt] - 2.0 * acc[mt][nt][j];
                acc[mt][nt][j] = v;
                rmax = fmax(rmax, v);
            }
    #pragma unroll
    for (int off = 32; off > 0; off >>= 1) rmax = fmax(rmax, __shfl_down(rmax, off, 64));
    if ((t & 63) == 0)
        atomicMax(d2max_p, (unsigned long long)__double_as_longlong(fmax(rmax, 0.0)));

    #pragma unroll
    for (int mt = 0; mt < 2; mt++)
        #pragma unroll
        for (int j = 0; j < 4; j++) {
            double m5[KNN];
            #pragma unroll
            for (int k = 0; k < KNN; k++) m5[k] = 1e300;
            #pragma unroll
            for (int nt = 0; nt < 8; nt++) ins5s(m5, acc[mt][nt][j]);
            bfly5s(m5, 1); bfly5s(m5, 2); bfly5s(m5, 4); bfly5s(m5, 8);
            if (r == 0) {
                int row = w32 + mt * 16 + irow[j];
                float* outp = &rec_dir[(size_t)blockIdx.x * (TP * KNN) + row * KNN];
                #pragma unroll
                for (int k = 0; k < KNN; k++) outp[k] = (float)m5[k];
            }
        }

    if (bi != bj) {
        double* M = S;
        #pragma unroll
        for (int nt = 0; nt < 8; nt++) {
            double m5[KNN];
            #pragma unroll
            for (int k = 0; k < KNN; k++) m5[k] = 1e300;
            #pragma unroll
            for (int mt = 0; mt < 2; mt++)
                #pragma unroll
                for (int j = 0; j < 4; j++) ins5s(m5, acc[mt][nt][j]);
            bfly5s(m5, 16); bfly5s(m5, 32);
            if (g == 0) {
                int col = nt * 16 + r;
                #pragma unroll
                for (int k = 0; k < KNN; k++) M[col * 21 + w * 5 + k] = m5[k];
            }
        }
        __syncthreads();
        if (t < 128) {
            float m5[KNN];
            #pragma unroll
            for (int k = 0; k < KNN; k++) m5[k] = (float)M[t * 21 + k];
            float o5[KNN];
            #pragma unroll
            for (int k = 0; k < KNN; k++) o5[k] = (float)M[t * 21 + 5 + k];
            merge5f(m5, o5);
            #pragma unroll
            for (int k = 0; k < KNN; k++) o5[k] = (float)M[t * 21 + 10 + k];
            merge5f(m5, o5);
            #pragma unroll
            for (int k = 0; k < KNN; k++) o5[k] = (float)M[t * 21 + 15 + k];
            merge5f(m5, o5);
            float* outp = &rec_tr[(size_t)blockIdx.x * (TP * KNN) + t * KNN];
            #pragma unroll
            for (int k = 0; k < KNN; k++) outp[k] = m5[k];
        }
    }
}

// ---------------------------------------------------------------------------
// Merge symA records -> density.  One WAVE per row; f32 merges (exact
// selection), f64 final math.  (structure proven R16)
// ---------------------------------------------------------------------------
__global__ void density_merge_sym_kernel(const float* __restrict__ rec_dir,
                                         const float* __restrict__ rec_tr,
                                         const float* __restrict__ noise,
                                         double* __restrict__ density)
{
    int i = (blockIdx.x * blockDim.x + threadIdx.x) >> 6;   // row = global wave
    int l = threadIdx.x & 63;
    if (i >= N) return;
    int T = i >> 7, rr = i & 127;
    int ndir = NTILE - T;
    float m5[KNN];
    if (l < ndir) {
        int bj = T + l;
        int p = bj * (bj + 1) / 2 + T;
        const float* rp = &rec_dir[(size_t)p * (TP * KNN) + rr * KNN];
        #pragma unroll
        for (int k = 0; k < KNN; k++) m5[k] = rp[k];
    } else {
        int b2 = l - ndir;
        int cumT = T * (T + 1) / 2;
        const float* rp = &rec_tr[(size_t)(cumT + b2) * (TP * KNN) + rr * KNN];
        #pragma unroll
        for (int k = 0; k < KNN; k++) m5[k] = rp[k];
    }
    bfly5f(m5, 1); bfly5f(m5, 2); bfly5f(m5, 4);
    bfly5f(m5, 8); bfly5f(m5, 16); bfly5f(m5, 32);
    if (l == 0) {
        double s2 = 0.0;
        #pragma unroll
        for (int k = 0; k < KNN; k++) {
            double z = m5[k] > 0.0f ? (double)m5[k] : 0.0;
            double d = sqrt(z) / SQRT_C;
            s2 += d * d;
        }
        density[i] = exp(-s2 / 5.0) + (double)(noise[i] * 1e-6f);
    }
}

// ---------------------------------------------------------------------------
// parent_min: coalesced float4 loads of the PERMUTED d2 tiles, then the
// proven symB masked-min epilogue (density compares in f64, mins in f32).
// ---------------------------------------------------------------------------
__launch_bounds__(256)
__global__ void parent_min_kernel(const float* __restrict__ rec_d2,
                                  const double* __restrict__ density,
                                  unsigned long long* __restrict__ gmin)
{
    int bi, bj;
    pair_decode(blockIdx.x, bi, bj);
    const int i0 = bi * TP, j0 = bj * TP;
    const int t = threadIdx.x;
    const int r = t & 15;
    const int g = (t >> 4) & 3;
    const int w = t >> 6;
    const int w32 = w * 32;
    const float4* tile = (const float4*)(rec_d2 + (size_t)blockIdx.x * (TP * TP));

    float4 acc[2][8];
    #pragma unroll
    for (int mt = 0; mt < 2; mt++)
        #pragma unroll
        for (int nt = 0; nt < 8; nt++)
            acc[mt][nt] = tile[(mt * 8 + nt) * 256 + t];

    double di[2][4], dj[8];
    float dmr[2][4], dmc[8];
    #pragma unroll
    for (int mt = 0; mt < 2; mt++)
        #pragma unroll
        for (int j = 0; j < 4; j++) {
            di[mt][j] = density[i0 + w32 + mt * 16 + g * 4 + j];
            dmr[mt][j] = 3.0e38f;
        }
    #pragma unroll
    for (int nt = 0; nt < 8; nt++) {
        dj[nt] = density[j0 + nt * 16 + r];
        dmc[nt] = 3.0e38f;
    }

    #pragma unroll
    for (int mt = 0; mt < 2; mt++)
        #pragma unroll
        for (int nt = 0; nt < 8; nt++) {
            float4 v4 = acc[mt][nt];
            float vv[4] = {v4.x, v4.y, v4.z, v4.w};
            #pragma unroll
            for (int j = 0; j < 4; j++) {
                float v = vv[j];
                if (dj[nt] > di[mt][j]) dmr[mt][j] = fminf(dmr[mt][j], v);
                if (di[mt][j] > dj[nt]) dmc[nt] = fminf(dmc[nt], v);
            }
        }

    // rows: butterfly over r lanes; r==0 atomicMin
    #pragma unroll
    for (int mt = 0; mt < 2; mt++)
        #pragma unroll
        for (int j = 0; j < 4; j++) {
            #pragma unroll
            for (int m = 1; m <= 8; m <<= 1)
                dmr[mt][j] = fminf(dmr[mt][j], __shfl_xor(dmr[mt][j], m, 64));
        }
    if (r == 0) {
        #pragma unroll
        for (int mt = 0; mt < 2; mt++)
            #pragma unroll
            for (int j = 0; j < 4; j++)
                if (dmr[mt][j] < 1.0e38f) {
                    int row = w32 + mt * 16 + g * 4 + j;
                    atomicMin(&gmin[i0 + row], dmap((double)dmr[mt][j]));
                }
    }
    // cols: butterfly over g (16,32); g==0 atomicMin
    if (bi != bj) {
        #pragma unroll
        for (int nt = 0; nt < 8; nt++) {
            #pragma unroll
            for (int m = 16; m <= 32; m <<= 1)
                dmc[nt] = fminf(dmc[nt], __shfl_xor(dmc[nt], m, 64));
        }
        if (g == 0) {
            #pragma unroll
            for (int nt = 0; nt < 8; nt++)
                if (dmc[nt] < 1.0e38f) {
                    int col = nt * 16 + r;
                    atomicMin(&gmin[j0 + col], dmap((double)dmc[nt]));
                }
        }
    }
}

// ---------------------------------------------------------------------------
// symB (fallback): f64 GEMM recompute + masked row/col mins.  (proven)
// ---------------------------------------------------------------------------
__launch_bounds__(256, 2)
__global__ void symB_kernel(const float* __restrict__ X,
                            const double* __restrict__ sq,
                            const double* __restrict__ density,
                            unsigned long long* __restrict__ gmin)
{
    __shared__ __align__(16) double S[2 * CH * PJ];
    double* As = S;
    double* Bs = S + CH * PJ;

    const int t = threadIdx.x;
    const int r = t & 15;
    const int g = (t >> 4) & 3;
    const int w = t >> 6;
    const int w32 = w * 32;
    int bi, bj;
    pair_decode(blockIdx.x, bi, bj);
    const int i0 = bi * TP, j0 = bj * TP;
    const float4* X4 = (const float4*)X;

    int irow[4];
    probe_rows(t, r, irow);

    d4 acc[2][8];
    #pragma unroll
    for (int mt = 0; mt < 2; mt++)
        #pragma unroll
        for (int nt = 0; nt < 8; nt++) acc[mt][nt] = (d4){0.0, 0.0, 0.0, 0.0};

    MFMA_GEMM_BODY(acc, As, Bs, X4, i0, j0, t, r, g, w32)

    double sqa[2][4], di[2][4], sqj[8], dj[8], dmr[2][4], dmc[8];
    #pragma unroll
    for (int mt = 0; mt < 2; mt++)
        #pragma unroll
        for (int j = 0; j < 4; j++) {
            int row = w32 + mt * 16 + irow[j];
            sqa[mt][j] = sq[i0 + row];
            di[mt][j] = density[i0 + row];
            dmr[mt][j] = 1e300;
        }
    #pragma unroll
    for (int nt = 0; nt < 8; nt++) {
        int col = nt * 16 + r;
        sqj[nt] = sq[j0 + col];
        dj[nt] = density[j0 + col];
        dmc[nt] = 1e300;
    }

    #pragma unroll
    for (int mt = 0; mt < 2; mt++)
        #pragma unroll
        for (int nt = 0; nt < 8; nt++)
            #pragma unroll
            for (int j = 0; j < 4; j++) {
                double v = sqa[mt][j] + sqj[nt] - 2.0 * acc[mt][nt][j];
                if (dj[nt] > di[mt][j]) dmr[mt][j] = fmin(dmr[mt][j], v);
                if (di[mt][j] > dj[nt]) dmc[nt] = fmin(dmc[nt], v);
            }

    #pragma unroll
    for (int mt = 0; mt < 2; mt++)
        #pragma unroll
        for (int j = 0; j < 4; j++) {
            #pragma unroll
            for (int m = 1; m <= 8; m <<= 1)
                dmr[mt][j] = fmin(dmr[mt][j], __shfl_xor(dmr[mt][j], m, 64));
        }
    if (r == 0) {
        #pragma unroll
        for (int mt = 0; mt < 2; mt++)
            #pragma unroll
            for (int j = 0; j < 4; j++)
                if (dmr[mt][j] < 9.9e299) {
                    int row = w32 + mt * 16 + irow[j];
                    atomicMin(&gmin[i0 + row], dmap(dmr[mt][j]));
                }
    }
    if (bi != bj) {
        #pragma unroll
        for (int nt = 0; nt < 8; nt++) {
            #pragma unroll
            for (int m = 16; m <= 32; m <<= 1)
                dmc[nt] = fmin(dmc[nt], __shfl_xor(dmc[nt], m, 64));
        }
        if (g == 0) {
            #pragma unroll
            for (int nt = 0; nt < 8; nt++)
                if (dmc[nt] < 9.9e299) {
                    int col = nt * 16 + r;
                    atomicMin(&gmin[j0 + col], dmap(dmc[nt]));
                }
        }
    }
}

// ---------------------------------------------------------------------------
__global__ void score_sym_kernel(const unsigned long long* __restrict__ gmin,
                                 const double* __restrict__ density,
                                 const unsigned long long* __restrict__ d2max_p,
                                 double* __restrict__ score)
{
    int i = blockIdx.x * blockDim.x + threadIdx.x;
    if (i >= N) return;
    unsigned long long u = gmin[i];
    double d2m = __longlong_as_double((long long)(*d2max_p));
    double distmax = sqrt(fmax(d2m, 0.0)) / SQRT_C;
    double dp;
    if (u == 0xFFFFFFFFFFFFFFFFull) {
        dp = distmax;
    } else {
        double dmin = dunmap(u);
        dp = sqrt(fmax(dmin, 0.0)) / SQRT_C;
    }
    score[i] = dp * density[i];
}

// ---------------------------------------------------------------------------
// Stable descending rank; 512 blocks, 16-way j-split per row, shuffle reduce.
// ---------------------------------------------------------------------------
__launch_bounds__(256)
__global__ void rank_kernel(const double* __restrict__ score, int* __restrict__ out)
{
    __shared__ double Ss[N];   // 64 KB
    for (int k = 0; k < N / 256; k++) {
        int idx = threadIdx.x + 256 * k;
        Ss[idx] = score[idx];
    }
    __syncthreads();
    int il = threadIdx.x >> 4;          // 0..15
    int ch = threadIdx.x & 15;          // 0..15
    int i = blockIdx.x * 16 + il;
    double si = Ss[i];
    int cnt = 0;
    for (int q = 0; q < N / 16; q++) {
        int j = ch + (q << 4);
        double sj = Ss[j];
        cnt += (sj > si) || (sj == si && j < i);
    }
    cnt += __shfl_down(cnt, 8, 16);
    cnt += __shfl_down(cnt, 4, 16);
    cnt += __shfl_down(cnt, 2, 16);
    cnt += __shfl_down(cnt, 1, 16);
    if (ch == 0 && cnt < NC) out[cnt] = i;
}

// ---------------------------------------------------------------------------
extern "C" void kernel_launch(void* const* d_in, const int* in_sizes, int n_in,
                              void* d_out, int out_size, void* d_ws, size_t ws_size,
                              hipStream_t stream) {
    const float* X = (const float*)d_in[0];
    int* out = (int*)d_out;

    double* ws      = (double*)d_ws;
    double* sq      = ws;                      // 8192
    double* density = ws + 8192;               // 8192
    double* score   = ws + 16384;              // 8192
    unsigned long long* d2max = (unsigned long long*)(ws + 24576);
    unsigned long long* gmin  = (unsigned long long*)(ws + 24584);  // 8192
    float*  noise   = (float*)(ws + 32776);    // 8192 floats  (ends ~294 KB)

    // bf16 planes at 1/3/5 MB (2 MB each)
    __bf16* X1 = (__bf16*)((char*)d_ws + (1ull << 20));
    __bf16* X2 = (__bf16*)((char*)d_ws + (3ull << 20));
    __bf16* X3 = (__bf16*)((char*)d_ws + (5ull << 20));

    // f32 records + f32 d2 tiles from 8 MB
    const size_t REC_OFF    = 8ull << 20;
    const size_t rec_elems  = (size_t)NPAIR * TP * KNN;   // 1,331,200
    const size_t tile_elems = (size_t)NPAIR * TP * TP;    // 34,078,720
    float* rec_dir = (float*)((char*)d_ws + REC_OFF);
    float* rec_tr  = rec_dir + rec_elems;
    float* rec_d2  = rec_tr + rec_elems;
    const size_t need = REC_OFF + (2 * rec_elems + tile_elems) * sizeof(float);  // ~155.4 MB

    setup_kernel<<<N / 4, 256, 0, stream>>>(X, sq, d2max, gmin, noise, X1, X2, X3);

    if (ws_size >= need) {
        // bf16x3 split-GEMM path (f32-precision d2, stored tiles, no recompute)
        symA_bf16_kernel<<<NPAIR, 256, 0, stream>>>(X1, X2, X3, sq, rec_dir, rec_tr, rec_d2, d2max);
        density_merge_sym_kernel<<<N * 64 / 256, 256, 0, stream>>>(rec_dir, rec_tr, noise, density);
        parent_min_kernel<<<NPAIR, 256, 0, stream>>>(rec_d2, density, gmin);
    } else {
        // proven f64 fallback (GEMM recompute in symB)
        symA_f64_kernel<<<NPAIR, 256, 0, stream>>>(X, sq, rec_dir, rec_tr, d2max);
        density_merge_sym_kernel<<<N * 64 / 256, 256, 0, stream>>>(rec_dir, rec_tr, noise, density);
        symB_kernel<<<NPAIR, 256, 0, stream>>>(X, sq, density, gmin);
    }

    score_sym_kernel<<<N / 256, 256, 0, stream>>>(gmin, density, d2max, score);
    rank_kernel<<<N / 16, 256, 0, stream>>>(score, out);
}

// Round 7
// 246.167 us; speedup vs baseline: 1.0319x; 1.0319x over previous
//
#include <hip/hip_runtime.h>
#include <math.h>

#define N 8192
#define C 128
#define NC 256
#define KNN 5

#define TP 128                        // tile size
#define NTILE (N / TP)                // 64
#define NPAIR (NTILE * (NTILE + 1) / 2)   // 2080
#define CH 16                         // channels per staging chunk (f64 path)
#define PJ 130                        // LDS pitch over row-dim (f64 path)
#define SQRT_C 11.313708498984761     // sqrt(128)

typedef double d4 __attribute__((ext_vector_type(4)));
using bf16x8 = __attribute__((ext_vector_type(8))) __bf16;
using f32x4  = __attribute__((ext_vector_type(4))) float;

static __device__ __forceinline__ unsigned rotl32(unsigned x, unsigned r) {
    return (x << r) | (x >> (32u - r));
}

// order-preserving double -> uint64 map (ascending)
static __device__ __forceinline__ unsigned long long dmap(double x) {
    long long b = __double_as_longlong(x);
    unsigned long long u = (unsigned long long)b;
    return (b >= 0) ? (u | 0x8000000000000000ull) : ~u;
}
static __device__ __forceinline__ double dunmap(unsigned long long u) {
    if (u & 0x8000000000000000ull) return __longlong_as_double((long long)(u ^ 0x8000000000000000ull));
    return __longlong_as_double((long long)(~u));
}

// async global->LDS, 16B per lane (dest = wave-uniform base + lane*16)
static __device__ __forceinline__ void gl_lds16(const void* g, void* l) {
    __builtin_amdgcn_global_load_lds(
        (const __attribute__((address_space(1))) void*)g,
        (__attribute__((address_space(3))) void*)l,
        16, 0, 0);
}

// ---------------------------------------------------------------------------
// Branchless sorted top-5 (ascending), f64 (fallback path).  (proven R13)
static __device__ __forceinline__ void ins5s(double (&m)[KNN], double v) {
    m[4] = fmin(m[4], fmax(m[3], v));
    m[3] = fmin(m[3], fmax(m[2], v));
    m[2] = fmin(m[2], fmax(m[1], v));
    m[1] = fmin(m[1], fmax(m[0], v));
    m[0] = fmin(m[0], v);
}
static __device__ __forceinline__ void sort5(double (&m)[KNN]) {
    double lo, hi;
#define CE(i, j) lo = fmin(m[i], m[j]); hi = fmax(m[i], m[j]); m[i] = lo; m[j] = hi;
    CE(0,1) CE(3,4) CE(2,4) CE(2,3) CE(0,3) CE(0,2) CE(1,4) CE(1,3) CE(1,2)
#undef CE
}
static __device__ __forceinline__ void bfly5s(double (&m)[KNN], int mask) {
    double pv[KNN];
    #pragma unroll
    for (int k = 0; k < KNN; k++) pv[k] = __shfl_xor(m[4 - k], mask, 64);
    #pragma unroll
    for (int k = 0; k < KNN; k++) m[k] = fmin(m[k], pv[k]);
    sort5(m);
}

// ---------------------------------------------------------------------------
// f32 versions (bf16 path).  Pure selection networks on f32 values: exact.
static __device__ __forceinline__ void ins5f(float (&m)[KNN], float v) {
    m[4] = fminf(m[4], fmaxf(m[3], v));
    m[3] = fminf(m[3], fmaxf(m[2], v));
    m[2] = fminf(m[2], fmaxf(m[1], v));
    m[1] = fminf(m[1], fmaxf(m[0], v));
    m[0] = fminf(m[0], v);
}
static __device__ __forceinline__ void sort5f(float (&m)[KNN]) {
    float lo, hi;
#define CE(i, j) lo = fminf(m[i], m[j]); hi = fmaxf(m[i], m[j]); m[i] = lo; m[j] = hi;
    CE(0,1) CE(3,4) CE(2,4) CE(2,3) CE(0,3) CE(0,2) CE(1,4) CE(1,3) CE(1,2)
#undef CE
}
static __device__ __forceinline__ void bfly5f(float (&m)[KNN], int mask) {
    float pv[KNN];
    #pragma unroll
    for (int k = 0; k < KNN; k++) pv[k] = __shfl_xor(m[4 - k], mask, 64);
    #pragma unroll
    for (int k = 0; k < KNN; k++) m[k] = fminf(m[k], pv[k]);
    sort5f(m);
}
static __device__ __forceinline__ void merge5f(float (&m)[KNN], const float* l) {
    #pragma unroll
    for (int k = 0; k < KNN; k++) m[k] = fminf(m[k], l[4 - k]);
    sort5f(m);
}

// ---------------------------------------------------------------------------
// f64 MFMA D-layout probe (proven R15) — fallback path only.
static __device__ __forceinline__ void probe_rows(int t, int r, int (&irow)[4]) {
    d4 pd = (d4){0.0, 0.0, 0.0, 0.0};
    pd = __builtin_amdgcn_mfma_f64_16x16x4f64((double)r, (r == 0) ? 1.0 : 0.0,
                                              pd, 0, 0, 0);
    #pragma unroll
    for (int j = 0; j < 4; j++) {
        double rv = __shfl(pd[j], t & 48, 64);   // group root lane 16*g
        irow[j] = (int)(rv * 0.25);
    }
}

// ---------------------------------------------------------------------------
// Fused setup: sq + gmin/d2max init + threefry noise + bf16x3 plane split.
// Planes are stored CHANNEL-BLOCKED: Xp[kg][point][8ch], kg = c>>3.
// -> staging reads of 16B/lane over consecutive points are fully coalesced.
// ---------------------------------------------------------------------------
__global__ void setup_kernel(const float* __restrict__ X,
                             double* __restrict__ sq,
                             unsigned long long* __restrict__ d2max,
                             unsigned long long* __restrict__ gmin,
                             float* __restrict__ noise,
                             __bf16* __restrict__ X1,
                             __bf16* __restrict__ X2,
                             __bf16* __restrict__ X3)
{
    int gid = blockIdx.x * blockDim.x + threadIdx.x;
    int wave = gid >> 6;
    int lane = threadIdx.x & 63;

    if (wave < N) {
        float f0 = X[wave * C + lane];
        float f1 = X[wave * C + 64 + lane];
        double v0 = (double)f0, v1 = (double)f1;
        double s = v0 * v0 + v1 * v1;
        #pragma unroll
        for (int off = 32; off > 0; off >>= 1) s += __shfl_down(s, off, 64);
        if (lane == 0) sq[wave] = s;

        // split f32 -> 3 bf16 planes (RNE at each stage), blocked layout
        __bf16 a0 = (__bf16)f0; float r0 = f0 - (float)a0;
        __bf16 b0 = (__bf16)r0; r0 -= (float)b0;
        __bf16 c0 = (__bf16)r0;
        __bf16 a1 = (__bf16)f1; float r1 = f1 - (float)a1;
        __bf16 b1 = (__bf16)r1; r1 -= (float)b1;
        __bf16 c1 = (__bf16)r1;
        int cA = lane, cB = lane + 64;
        size_t iA = (size_t)(cA >> 3) * (N * 8) + (size_t)wave * 8 + (cA & 7);
        size_t iB = (size_t)(cB >> 3) * (N * 8) + (size_t)wave * 8 + (cB & 7);
        X1[iA] = a0;  X1[iB] = a1;
        X2[iA] = b0;  X2[iB] = b1;
        X3[iA] = c0;  X3[iB] = c1;
    }
    if (gid < N) gmin[gid] = 0xFFFFFFFFFFFFFFFFull;
    if (gid == 0) *d2max = 0ull;
    if (gid < N / 2) {
        int j = gid;
        const unsigned ks0 = 0u, ks1 = 1u;
        const unsigned ks2 = 0x1BD11BDAu ^ ks0 ^ ks1;
        unsigned x0 = (unsigned)j + ks0;
        unsigned x1 = (unsigned)(j + N / 2) + ks1;
        const unsigned rotA[4] = {13u, 15u, 26u, 6u};
        const unsigned rotB[4] = {17u, 29u, 16u, 24u};
        #pragma unroll
        for (int q = 0; q < 4; q++) { x0 += x1; x1 = rotl32(x1, rotA[q]); x1 ^= x0; }
        x0 += ks1; x1 += ks2 + 1u;
        #pragma unroll
        for (int q = 0; q < 4; q++) { x0 += x1; x1 = rotl32(x1, rotB[q]); x1 ^= x0; }
        x0 += ks2; x1 += ks0 + 2u;
        #pragma unroll
        for (int q = 0; q < 4; q++) { x0 += x1; x1 = rotl32(x1, rotA[q]); x1 ^= x0; }
        x0 += ks0; x1 += ks1 + 3u;
        #pragma unroll
        for (int q = 0; q < 4; q++) { x0 += x1; x1 = rotl32(x1, rotB[q]); x1 ^= x0; }
        x0 += ks1; x1 += ks2 + 4u;
        #pragma unroll
        for (int q = 0; q < 4; q++) { x0 += x1; x1 = rotl32(x1, rotA[q]); x1 ^= x0; }
        x0 += ks2; x1 += ks0 + 5u;
        unsigned b0u = (x0 >> 9) | 0x3f800000u;
        unsigned b1u = (x1 >> 9) | 0x3f800000u;
        noise[j]         = __uint_as_float(b0u) - 1.0f;
        noise[j + N / 2] = __uint_as_float(b1u) - 1.0f;
    }
}

// p = bj*(bj+1)/2 + bi, bi <= bj
static __device__ __forceinline__ void pair_decode(int p, int& bi, int& bj) {
    int b = (int)((sqrt(8.0 * (double)p + 1.0) - 1.0) * 0.5);
    while ((b + 1) * (b + 2) / 2 <= p) b++;
    while (b * (b + 1) / 2 > p) b--;
    bj = b;
    bi = p - b * (b + 1) / 2;
}

// ---------------------------------------------------------------------------
// symA_bf16: bf16x3 split-GEMM via v_mfma_f32_16x16x32_bf16.
// Planes are channel-blocked [kg][point][8ch] -> all staging COALESCED:
//  - B: gl_lds16, lane l reads 16B at (kg*(N*8) + (j0+p0+l)*8)*2B — 1KB/instr
//    contiguous.  Linear LDS dest, double-buffered.  Zero staging VGPRs.
//  - A: per-lane direct bf16x8 loads, 4 contiguous 256B segments per wave,
//    pipelined one chunk ahead.
//  - acc bit-identical to R5/R6 (same LDS slots, same MFMA order).
// ---------------------------------------------------------------------------
__launch_bounds__(256, 2)
__global__ void symA_bf16_kernel(const __bf16* __restrict__ X1,
                                 const __bf16* __restrict__ X2,
                                 const __bf16* __restrict__ X3,
                                 const double* __restrict__ sq,
                                 float* __restrict__ rec_dir,
                                 float* __restrict__ rec_tr,
                                 float* __restrict__ rec_d2,
                                 unsigned long long* __restrict__ d2max_p)
{
    __shared__ __align__(16) float4 Sb[2 * 1536];   // 49,152 B (double-buffered B)

    const int t = threadIdx.x;
    const int r = t & 15;
    const int g = (t >> 4) & 3;
    const int w = t >> 6;
    const int l = t & 63;
    const int w32 = w * 32;
    int bi, bj;
    pair_decode(blockIdx.x, bi, bj);
    const int i0 = bi * TP, j0 = bj * TP;

    f32x4 acc[2][8];
    #pragma unroll
    for (int mt = 0; mt < 2; mt++)
        #pragma unroll
        for (int nt = 0; nt < 8; nt++) acc[mt][nt] = (f32x4){0.f, 0.f, 0.f, 0.f};

    const int kgw = (w >> 1);
    const int p0  = (w & 1) * 64;

#define STAGE_B(ck, buf)                                                       \
    {                                                                          \
        _Pragma("unroll")                                                      \
        for (int pl = 0; pl < 3; pl++) {                                       \
            const __bf16* P = (pl == 0) ? X1 : ((pl == 1) ? X2 : X3);          \
            _Pragma("unroll")                                                  \
            for (int h = 0; h < 2; h++) {                                      \
                int kg = (ck) * 4 + h * 2 + kgw;                               \
                const __bf16* gp = P + (size_t)kg * (N * 8)                    \
                                     + (size_t)(j0 + p0 + l) * 8;              \
                float4* lp = Sb + (buf) * 1536 + pl * 512 + h * 256 + w * 64;  \
                gl_lds16((const void*)gp, (void*)lp);                          \
            }                                                                  \
        }                                                                      \
    }

#define LOAD_A(ck, areg)                                                       \
    {                                                                          \
        size_t kga = (size_t)((ck) * 4 + g) * (N * 8);                         \
        size_t a0o = kga + (size_t)(i0 + w32 + r) * 8;                         \
        size_t a1o = kga + (size_t)(i0 + w32 + 16 + r) * 8;                    \
        areg[0][0] = *(const bf16x8*)(X1 + a0o);                               \
        areg[0][1] = *(const bf16x8*)(X2 + a0o);                               \
        areg[0][2] = *(const bf16x8*)(X3 + a0o);                               \
        areg[1][0] = *(const bf16x8*)(X1 + a1o);                               \
        areg[1][1] = *(const bf16x8*)(X2 + a1o);                               \
        areg[1][2] = *(const bf16x8*)(X3 + a1o);                               \
    }

    bf16x8 areg[2][2][3];   // [parity][mt][pl] — static-indexed after unroll

    // prologue: A(0) + stage B(0) into buffer 0
    LOAD_A(0, areg[0])
    STAGE_B(0, 0)
    __syncthreads();

    #pragma unroll
    for (int ck = 0; ck < 4; ck++) {
        const int cur = ck & 1;
        if (ck < 3) {
            STAGE_B(ck + 1, cur ^ 1)      // async global->LDS (next B)
            LOAD_A(ck + 1, areg[cur ^ 1]) // global->VGPR (next A, drains at barrier)
        }
        const bf16x8* SB = (const bf16x8*)Sb + (size_t)cur * 1536;
        #pragma unroll
        for (int nt = 0; nt < 8; nt++) {
            bf16x8 b0 = SB[0 * 512 + g * 128 + nt * 16 + r];
            bf16x8 b1 = SB[1 * 512 + g * 128 + nt * 16 + r];
            bf16x8 b2 = SB[2 * 512 + g * 128 + nt * 16 + r];
            #pragma unroll
            for (int mt = 0; mt < 2; mt++) {
                f32x4 c = acc[mt][nt];
                c = __builtin_amdgcn_mfma_f32_16x16x32_bf16(areg[cur][mt][0], b0, c, 0, 0, 0);
                c = __builtin_amdgcn_mfma_f32_16x16x32_bf16(areg[cur][mt][0], b1, c, 0, 0, 0);
                c = __builtin_amdgcn_mfma_f32_16x16x32_bf16(areg[cur][mt][1], b0, c, 0, 0, 0);
                c = __builtin_amdgcn_mfma_f32_16x16x32_bf16(areg[cur][mt][0], b2, c, 0, 0, 0);
                c = __builtin_amdgcn_mfma_f32_16x16x32_bf16(areg[cur][mt][2], b0, c, 0, 0, 0);
                c = __builtin_amdgcn_mfma_f32_16x16x32_bf16(areg[cur][mt][1], b1, c, 0, 0, 0);
                acc[mt][nt] = c;
            }
        }
        __syncthreads();   // drains vmcnt -> next buffer + next A ready
    }
#undef STAGE_B
#undef LOAD_A

    // d2 in place (f32) + wave max -> global atomic
    double sqa[2][4], sqj[8];
    #pragma unroll
    for (int mt = 0; mt < 2; mt++)
        #pragma unroll
        for (int j = 0; j < 4; j++) sqa[mt][j] = sq[i0 + w32 + mt * 16 + g * 4 + j];
    #pragma unroll
    for (int nt = 0; nt < 8; nt++) sqj[nt] = sq[j0 + nt * 16 + r];
    double rmax = 0.0;
    #pragma unroll
    for (int mt = 0; mt < 2; mt++)
        #pragma unroll
        for (int nt = 0; nt < 8; nt++)
            #pragma unroll
            for (int j = 0; j < 4; j++) {
                double v = sqa[mt][j] + sqj[nt] - 2.0 * (double)acc[mt][nt][j];
                acc[mt][nt][j] = (float)v;
                rmax = fmax(rmax, v);
            }
    #pragma unroll
    for (int off = 32; off > 0; off >>= 1) rmax = fmax(rmax, __shfl_down(rmax, off, 64));
    if ((t & 63) == 0)
        atomicMax(d2max_p, (unsigned long long)__double_as_longlong(fmax(rmax, 0.0)));

    // ---- PERMUTED d2 store: lane's float4 at [(mt*8+nt)*256 + t]  (coalesced)
    {
        float4* outp = (float4*)(rec_d2 + (size_t)blockIdx.x * (TP * TP));
        #pragma unroll
        for (int mt = 0; mt < 2; mt++)
            #pragma unroll
            for (int nt = 0; nt < 8; nt++) {
                f32x4 v = acc[mt][nt];
                outp[(mt * 8 + nt) * 256 + t] = (float4){v[0], v[1], v[2], v[3]};
            }
    }

    // ---- rows: lane scans 8 nt values; bfly over r lanes; r==0 writes. (f32)
    #pragma unroll
    for (int mt = 0; mt < 2; mt++)
        #pragma unroll
        for (int j = 0; j < 4; j++) {
            float m5[KNN];
            #pragma unroll
            for (int k = 0; k < KNN; k++) m5[k] = 3.0e38f;
            #pragma unroll
            for (int nt = 0; nt < 8; nt++) ins5f(m5, acc[mt][nt][j]);
            bfly5f(m5, 1); bfly5f(m5, 2); bfly5f(m5, 4); bfly5f(m5, 8);
            if (r == 0) {
                int row = w32 + mt * 16 + g * 4 + j;
                float* outp = &rec_dir[(size_t)blockIdx.x * (TP * KNN) + row * KNN];
                #pragma unroll
                for (int k = 0; k < KNN; k++) outp[k] = m5[k];
            }
        }

    // ---- cols (off-diagonal): scan 8 (mt,j); bfly over g (16,32); LDS merge
    if (bi != bj) {
        float* M = (float*)Sb;   // [col][21] : 4 wave-partials x 5
        #pragma unroll
        for (int nt = 0; nt < 8; nt++) {
            float m5[KNN];
            #pragma unroll
            for (int k = 0; k < KNN; k++) m5[k] = 3.0e38f;
            #pragma unroll
            for (int mt = 0; mt < 2; mt++)
                #pragma unroll
                for (int j = 0; j < 4; j++) ins5f(m5, acc[mt][nt][j]);
            bfly5f(m5, 16); bfly5f(m5, 32);
            if (g == 0) {
                int col = nt * 16 + r;
                #pragma unroll
                for (int k = 0; k < KNN; k++) M[col * 21 + w * 5 + k] = m5[k];
            }
        }
        __syncthreads();
        if (t < 128) {
            float m5[KNN];
            #pragma unroll
            for (int k = 0; k < KNN; k++) m5[k] = M[t * 21 + k];
            merge5f(m5, &M[t * 21 + 5]);
            merge5f(m5, &M[t * 21 + 10]);
            merge5f(m5, &M[t * 21 + 15]);
            float* outp = &rec_tr[(size_t)blockIdx.x * (TP * KNN) + t * KNN];
            #pragma unroll
            for (int k = 0; k < KNN; k++) outp[k] = m5[k];
        }
    }
}

// ---------------------------------------------------------------------------
// f64 MFMA GEMM body (proven) — fallback path only.
// ---------------------------------------------------------------------------
#define MFMA_GEMM_BODY(acc, As, Bs, X4, i0, j0, t, r, g, w32)                  \
    {                                                                          \
        float4 pa[2], pb[2];                                                   \
        _Pragma("unroll")                                                      \
        for (int q = 0; q < 2; q++) {                                          \
            int flat = t + 256 * q;                                            \
            int row = flat >> 2, c4 = flat & 3;                                \
            pa[q] = X4[(size_t)(i0 + row) * 32 + c4];                          \
            pb[q] = X4[(size_t)(j0 + row) * 32 + c4];                          \
        }                                                                      \
        for (int ck = 0; ck < 8; ck++) {                                       \
            _Pragma("unroll")                                                  \
            for (int q = 0; q < 2; q++) {                                      \
                int flat = t + 256 * q;                                        \
                int row = flat >> 2, c4 = flat & 3;                            \
                As[(4 * c4 + 0) * PJ + row] = (double)pa[q].x;                 \
                As[(4 * c4 + 1) * PJ + row] = (double)pa[q].y;                 \
                As[(4 * c4 + 2) * PJ + row] = (double)pa[q].z;                 \
                As[(4 * c4 + 3) * PJ + row] = (double)pa[q].w;                 \
                Bs[(4 * c4 + 0) * PJ + row] = (double)pb[q].x;                 \
                Bs[(4 * c4 + 1) * PJ + row] = (double)pb[q].y;                 \
                Bs[(4 * c4 + 2) * PJ + row] = (double)pb[q].z;                 \
                Bs[(4 * c4 + 3) * PJ + row] = (double)pb[q].w;                 \
            }                                                                  \
            __syncthreads();                                                   \
            if (ck < 7) {                                                      \
                _Pragma("unroll")                                              \
                for (int q = 0; q < 2; q++) {                                  \
                    int flat = t + 256 * q;                                    \
                    int row = flat >> 2, c4 = flat & 3;                        \
                    pa[q] = X4[(size_t)(i0 + row) * 32 + (ck + 1) * 4 + c4];   \
                    pb[q] = X4[(size_t)(j0 + row) * 32 + (ck + 1) * 4 + c4];   \
                }                                                              \
            }                                                                  \
            _Pragma("unroll")                                                  \
            for (int ks = 0; ks < 4; ks++) {                                   \
                int cc = 4 * ks + g;                                           \
                double a0 = As[cc * PJ + w32 + r];                             \
                double a1 = As[cc * PJ + w32 + 16 + r];                        \
                double bv[8];                                                  \
                _Pragma("unroll")                                              \
                for (int nt = 0; nt < 8; nt++) bv[nt] = Bs[cc * PJ + nt * 16 + r]; \
                _Pragma("unroll")                                              \
                for (int nt = 0; nt < 8; nt++)                                 \
                    acc[0][nt] = __builtin_amdgcn_mfma_f64_16x16x4f64(a0, bv[nt], acc[0][nt], 0, 0, 0); \
                _Pragma("unroll")                                              \
                for (int nt = 0; nt < 8; nt++)                                 \
                    acc[1][nt] = __builtin_amdgcn_mfma_f64_16x16x4f64(a1, bv[nt], acc[1][nt], 0, 0, 0); \
            }                                                                  \
            __syncthreads();                                                   \
        }                                                                      \
    }

// ---------------------------------------------------------------------------
// symA_f64 (fallback): proven f64 GEMM + top-5 epilogue, float records.
// ---------------------------------------------------------------------------
__launch_bounds__(256, 2)
__global__ void symA_f64_kernel(const float* __restrict__ X,
                                const double* __restrict__ sq,
                                float* __restrict__ rec_dir,
                                float* __restrict__ rec_tr,
                                unsigned long long* __restrict__ d2max_p)
{
    __shared__ __align__(16) double S[2 * CH * PJ];
    double* As = S;
    double* Bs = S + CH * PJ;

    const int t = threadIdx.x;
    const int r = t & 15;
    const int g = (t >> 4) & 3;
    const int w = t >> 6;
    const int w32 = w * 32;
    int bi, bj;
    pair_decode(blockIdx.x, bi, bj);
    const int i0 = bi * TP, j0 = bj * TP;
    const float4* X4 = (const float4*)X;

    int irow[4];
    probe_rows(t, r, irow);

    d4 acc[2][8];
    #pragma unroll
    for (int mt = 0; mt < 2; mt++)
        #pragma unroll
        for (int nt = 0; nt < 8; nt++) acc[mt][nt] = (d4){0.0, 0.0, 0.0, 0.0};

    MFMA_GEMM_BODY(acc, As, Bs, X4, i0, j0, t, r, g, w32)

    double sqa[2][4], sqj[8];
    #pragma unroll
    for (int mt = 0; mt < 2; mt++)
        #pragma unroll
        for (int j = 0; j < 4; j++) sqa[mt][j] = sq[i0 + w32 + mt * 16 + irow[j]];
    #pragma unroll
    for (int nt = 0; nt < 8; nt++) sqj[nt] = sq[j0 + nt * 16 + r];
    double rmax = 0.0;
    #pragma unroll
    for (int mt = 0; mt < 2; mt++)
        #pragma unroll
        for (int nt = 0; nt < 8; nt++)
            #pragma unroll
            for (int j = 0; j < 4; j++) {
                double v = sqa[mt][j] + sqj[nt] - 2.0 * acc[mt][nt][j];
                acc[mt][nt][j] = v;
                rmax = fmax(rmax, v);
            }
    #pragma unroll
    for (int off = 32; off > 0; off >>= 1) rmax = fmax(rmax, __shfl_down(rmax, off, 64));
    if ((t & 63) == 0)
        atomicMax(d2max_p, (unsigned long long)__double_as_longlong(fmax(rmax, 0.0)));

    #pragma unroll
    for (int mt = 0; mt < 2; mt++)
        #pragma unroll
        for (int j = 0; j < 4; j++) {
            double m5[KNN];
            #pragma unroll
            for (int k = 0; k < KNN; k++) m5[k] = 1e300;
            #pragma unroll
            for (int nt = 0; nt < 8; nt++) ins5s(m5, acc[mt][nt][j]);
            bfly5s(m5, 1); bfly5s(m5, 2); bfly5s(m5, 4); bfly5s(m5, 8);
            if (r == 0) {
                int row = w32 + mt * 16 + irow[j];
                float* outp = &rec_dir[(size_t)blockIdx.x * (TP * KNN) + row * KNN];
                #pragma unroll
                for (int k = 0; k < KNN; k++) outp[k] = (float)m5[k];
            }
        }

    if (bi != bj) {
        double* M = S;
        #pragma unroll
        for (int nt = 0; nt < 8; nt++) {
            double m5[KNN];
            #pragma unroll
            for (int k = 0; k < KNN; k++) m5[k] = 1e300;
            #pragma unroll
            for (int mt = 0; mt < 2; mt++)
                #pragma unroll
                for (int j = 0; j < 4; j++) ins5s(m5, acc[mt][nt][j]);
            bfly5s(m5, 16); bfly5s(m5, 32);
            if (g == 0) {
                int col = nt * 16 + r;
                #pragma unroll
                for (int k = 0; k < KNN; k++) M[col * 21 + w * 5 + k] = m5[k];
            }
        }
        __syncthreads();
        if (t < 128) {
            float m5[KNN];
            #pragma unroll
            for (int k = 0; k < KNN; k++) m5[k] = (float)M[t * 21 + k];
            float o5[KNN];
            #pragma unroll
            for (int k = 0; k < KNN; k++) o5[k] = (float)M[t * 21 + 5 + k];
            merge5f(m5, o5);
            #pragma unroll
            for (int k = 0; k < KNN; k++) o5[k] = (float)M[t * 21 + 10 + k];
            merge5f(m5, o5);
            #pragma unroll
            for (int k = 0; k < KNN; k++) o5[k] = (float)M[t * 21 + 15 + k];
            merge5f(m5, o5);
            float* outp = &rec_tr[(size_t)blockIdx.x * (TP * KNN) + t * KNN];
            #pragma unroll
            for (int k = 0; k < KNN; k++) outp[k] = m5[k];
        }
    }
}

// ---------------------------------------------------------------------------
// Merge symA records -> density.  One WAVE per row; f32 merges (exact
// selection), f64 final math.  (structure proven R16)
// ---------------------------------------------------------------------------
__global__ void density_merge_sym_kernel(const float* __restrict__ rec_dir,
                                         const float* __restrict__ rec_tr,
                                         const float* __restrict__ noise,
                                         double* __restrict__ density)
{
    int i = (blockIdx.x * blockDim.x + threadIdx.x) >> 6;   // row = global wave
    int l = threadIdx.x & 63;
    if (i >= N) return;
    int T = i >> 7, rr = i & 127;
    int ndir = NTILE - T;
    float m5[KNN];
    if (l < ndir) {
        int bj = T + l;
        int p = bj * (bj + 1) / 2 + T;
        const float* rp = &rec_dir[(size_t)p * (TP * KNN) + rr * KNN];
        #pragma unroll
        for (int k = 0; k < KNN; k++) m5[k] = rp[k];
    } else {
        int b2 = l - ndir;
        int cumT = T * (T + 1) / 2;
        const float* rp = &rec_tr[(size_t)(cumT + b2) * (TP * KNN) + rr * KNN];
        #pragma unroll
        for (int k = 0; k < KNN; k++) m5[k] = rp[k];
    }
    bfly5f(m5, 1); bfly5f(m5, 2); bfly5f(m5, 4);
    bfly5f(m5, 8); bfly5f(m5, 16); bfly5f(m5, 32);
    if (l == 0) {
        double s2 = 0.0;
        #pragma unroll
        for (int k = 0; k < KNN; k++) {
            double z = m5[k] > 0.0f ? (double)m5[k] : 0.0;
            double d = sqrt(z) / SQRT_C;
            s2 += d * d;
        }
        density[i] = exp(-s2 / 5.0) + (double)(noise[i] * 1e-6f);
    }
}

// ---------------------------------------------------------------------------
// parent_min: coalesced float4 loads of the PERMUTED d2 tiles, then the
// proven symB masked-min epilogue (density compares in f64, mins in f32).
// ---------------------------------------------------------------------------
__launch_bounds__(256)
__global__ void parent_min_kernel(const float* __restrict__ rec_d2,
                                  const double* __restrict__ density,
                                  unsigned long long* __restrict__ gmin)
{
    int bi, bj;
    pair_decode(blockIdx.x, bi, bj);
    const int i0 = bi * TP, j0 = bj * TP;
    const int t = threadIdx.x;
    const int r = t & 15;
    const int g = (t >> 4) & 3;
    const int w = t >> 6;
    const int w32 = w * 32;
    const float4* tile = (const float4*)(rec_d2 + (size_t)blockIdx.x * (TP * TP));

    float4 acc[2][8];
    #pragma unroll
    for (int mt = 0; mt < 2; mt++)
        #pragma unroll
        for (int nt = 0; nt < 8; nt++)
            acc[mt][nt] = tile[(mt * 8 + nt) * 256 + t];

    double di[2][4], dj[8];
    float dmr[2][4], dmc[8];
    #pragma unroll
    for (int mt = 0; mt < 2; mt++)
        #pragma unroll
        for (int j = 0; j < 4; j++) {
            di[mt][j] = density[i0 + w32 + mt * 16 + g * 4 + j];
            dmr[mt][j] = 3.0e38f;
        }
    #pragma unroll
    for (int nt = 0; nt < 8; nt++) {
        dj[nt] = density[j0 + nt * 16 + r];
        dmc[nt] = 3.0e38f;
    }

    #pragma unroll
    for (int mt = 0; mt < 2; mt++)
        #pragma unroll
        for (int nt = 0; nt < 8; nt++) {
            float4 v4 = acc[mt][nt];
            float vv[4] = {v4.x, v4.y, v4.z, v4.w};
            #pragma unroll
            for (int j = 0; j < 4; j++) {
                float v = vv[j];
                if (dj[nt] > di[mt][j]) dmr[mt][j] = fminf(dmr[mt][j], v);
                if (di[mt][j] > dj[nt]) dmc[nt] = fminf(dmc[nt], v);
            }
        }

    // rows: butterfly over r lanes; r==0 atomicMin
    #pragma unroll
    for (int mt = 0; mt < 2; mt++)
        #pragma unroll
        for (int j = 0; j < 4; j++) {
            #pragma unroll
            for (int m = 1; m <= 8; m <<= 1)
                dmr[mt][j] = fminf(dmr[mt][j], __shfl_xor(dmr[mt][j], m, 64));
        }
    if (r == 0) {
        #pragma unroll
        for (int mt = 0; mt < 2; mt++)
            #pragma unroll
            for (int j = 0; j < 4; j++)
                if (dmr[mt][j] < 1.0e38f) {
                    int row = w32 + mt * 16 + g * 4 + j;
                    atomicMin(&gmin[i0 + row], dmap((double)dmr[mt][j]));
                }
    }
    // cols: butterfly over g (16,32); g==0 atomicMin
    if (bi != bj) {
        #pragma unroll
        for (int nt = 0; nt < 8; nt++) {
            #pragma unroll
            for (int m = 16; m <= 32; m <<= 1)
                dmc[nt] = fminf(dmc[nt], __shfl_xor(dmc[nt], m, 64));
        }
        if (g == 0) {
            #pragma unroll
            for (int nt = 0; nt < 8; nt++)
                if (dmc[nt] < 1.0e38f) {
                    int col = nt * 16 + r;
                    atomicMin(&gmin[j0 + col], dmap((double)dmc[nt]));
                }
        }
    }
}

// ---------------------------------------------------------------------------
// symB (fallback): f64 GEMM recompute + masked row/col mins.  (proven)
// ---------------------------------------------------------------------------
__launch_bounds__(256, 2)
__global__ void symB_kernel(const float* __restrict__ X,
                            const double* __restrict__ sq,
                            const double* __restrict__ density,
                            unsigned long long* __restrict__ gmin)
{
    __shared__ __align__(16) double S[2 * CH * PJ];
    double* As = S;
    double* Bs = S + CH * PJ;

    const int t = threadIdx.x;
    const int r = t & 15;
    const int g = (t >> 4) & 3;
    const int w = t >> 6;
    const int w32 = w * 32;
    int bi, bj;
    pair_decode(blockIdx.x, bi, bj);
    const int i0 = bi * TP, j0 = bj * TP;
    const float4* X4 = (const float4*)X;

    int irow[4];
    probe_rows(t, r, irow);

    d4 acc[2][8];
    #pragma unroll
    for (int mt = 0; mt < 2; mt++)
        #pragma unroll
        for (int nt = 0; nt < 8; nt++) acc[mt][nt] = (d4){0.0, 0.0, 0.0, 0.0};

    MFMA_GEMM_BODY(acc, As, Bs, X4, i0, j0, t, r, g, w32)

    double sqa[2][4], di[2][4], sqj[8], dj[8], dmr[2][4], dmc[8];
    #pragma unroll
    for (int mt = 0; mt < 2; mt++)
        #pragma unroll
        for (int j = 0; j < 4; j++) {
            int row = w32 + mt * 16 + irow[j];
            sqa[mt][j] = sq[i0 + row];
            di[mt][j] = density[i0 + row];
            dmr[mt][j] = 1e300;
        }
    #pragma unroll
    for (int nt = 0; nt < 8; nt++) {
        int col = nt * 16 + r;
        sqj[nt] = sq[j0 + col];
        dj[nt] = density[j0 + col];
        dmc[nt] = 1e300;
    }

    #pragma unroll
    for (int mt = 0; mt < 2; mt++)
        #pragma unroll
        for (int nt = 0; nt < 8; nt++)
            #pragma unroll
            for (int j = 0; j < 4; j++) {
                double v = sqa[mt][j] + sqj[nt] - 2.0 * acc[mt][nt][j];
                if (dj[nt] > di[mt][j]) dmr[mt][j] = fmin(dmr[mt][j], v);
                if (di[mt][j] > dj[nt]) dmc[nt] = fmin(dmc[nt], v);
            }

    #pragma unroll
    for (int mt = 0; mt < 2; mt++)
        #pragma unroll
        for (int j = 0; j < 4; j++) {
            #pragma unroll
            for (int m = 1; m <= 8; m <<= 1)
                dmr[mt][j] = fmin(dmr[mt][j], __shfl_xor(dmr[mt][j], m, 64));
        }
    if (r == 0) {
        #pragma unroll
        for (int mt = 0; mt < 2; mt++)
            #pragma unroll
            for (int j = 0; j < 4; j++)
                if (dmr[mt][j] < 9.9e299) {
                    int row = w32 + mt * 16 + irow[j];
                    atomicMin(&gmin[i0 + row], dmap(dmr[mt][j]));
                }
    }
    if (bi != bj) {
        #pragma unroll
        for (int nt = 0; nt < 8; nt++) {
            #pragma unroll
            for (int m = 16; m <= 32; m <<= 1)
                dmc[nt] = fmin(dmc[nt], __shfl_xor(dmc[nt], m, 64));
        }
        if (g == 0) {
            #pragma unroll
            for (int nt = 0; nt < 8; nt++)
                if (dmc[nt] < 9.9e299) {
                    int col = nt * 16 + r;
                    atomicMin(&gmin[j0 + col], dmap(dmc[nt]));
                }
        }
    }
}

// ---------------------------------------------------------------------------
__global__ void score_sym_kernel(const unsigned long long* __restrict__ gmin,
                                 const double* __restrict__ density,
                                 const unsigned long long* __restrict__ d2max_p,
                                 double* __restrict__ score)
{
    int i = blockIdx.x * blockDim.x + threadIdx.x;
    if (i >= N) return;
    unsigned long long u = gmin[i];
    double d2m = __longlong_as_double((long long)(*d2max_p));
    double distmax = sqrt(fmax(d2m, 0.0)) / SQRT_C;
    double dp;
    if (u == 0xFFFFFFFFFFFFFFFFull) {
        dp = distmax;
    } else {
        double dmin = dunmap(u);
        dp = sqrt(fmax(dmin, 0.0)) / SQRT_C;
    }
    score[i] = dp * density[i];
}

// ---------------------------------------------------------------------------
// Stable descending rank; 512 blocks, 16-way j-split per row, shuffle reduce.
// ---------------------------------------------------------------------------
__launch_bounds__(256)
__global__ void rank_kernel(const double* __restrict__ score, int* __restrict__ out)
{
    __shared__ double Ss[N];   // 64 KB
    for (int k = 0; k < N / 256; k++) {
        int idx = threadIdx.x + 256 * k;
        Ss[idx] = score[idx];
    }
    __syncthreads();
    int il = threadIdx.x >> 4;          // 0..15
    int ch = threadIdx.x & 15;          // 0..15
    int i = blockIdx.x * 16 + il;
    double si = Ss[i];
    int cnt = 0;
    for (int q = 0; q < N / 16; q++) {
        int j = ch + (q << 4);
        double sj = Ss[j];
        cnt += (sj > si) || (sj == si && j < i);
    }
    cnt += __shfl_down(cnt, 8, 16);
    cnt += __shfl_down(cnt, 4, 16);
    cnt += __shfl_down(cnt, 2, 16);
    cnt += __shfl_down(cnt, 1, 16);
    if (ch == 0 && cnt < NC) out[cnt] = i;
}

// ---------------------------------------------------------------------------
extern "C" void kernel_launch(void* const* d_in, const int* in_sizes, int n_in,
                              void* d_out, int out_size, void* d_ws, size_t ws_size,
                              hipStream_t stream) {
    const float* X = (const float*)d_in[0];
    int* out = (int*)d_out;

    double* ws      = (double*)d_ws;
    double* sq      = ws;                      // 8192
    double* density = ws + 8192;               // 8192
    double* score   = ws + 16384;              // 8192
    unsigned long long* d2max = (unsigned long long*)(ws + 24576);
    unsigned long long* gmin  = (unsigned long long*)(ws + 24584);  // 8192
    float*  noise   = (float*)(ws + 32776);    // 8192 floats  (ends ~294 KB)

    // bf16 planes at 1/3/5 MB (2 MB each), channel-blocked [kg][point][8]
    __bf16* X1 = (__bf16*)((char*)d_ws + (1ull << 20));
    __bf16* X2 = (__bf16*)((char*)d_ws + (3ull << 20));
    __bf16* X3 = (__bf16*)((char*)d_ws + (5ull << 20));

    // f32 records + f32 d2 tiles from 8 MB
    const size_t REC_OFF    = 8ull << 20;
    const size_t rec_elems  = (size_t)NPAIR * TP * KNN;   // 1,331,200
    const size_t tile_elems = (size_t)NPAIR * TP * TP;    // 34,078,720
    float* rec_dir = (float*)((char*)d_ws + REC_OFF);
    float* rec_tr  = rec_dir + rec_elems;
    float* rec_d2  = rec_tr + rec_elems;
    const size_t need = REC_OFF + (2 * rec_elems + tile_elems) * sizeof(float);  // ~155.4 MB

    setup_kernel<<<N / 4, 256, 0, stream>>>(X, sq, d2max, gmin, noise, X1, X2, X3);

    if (ws_size >= need) {
        // bf16x3 split-GEMM path (f32-precision d2, stored tiles, no recompute)
        symA_bf16_kernel<<<NPAIR, 256, 0, stream>>>(X1, X2, X3, sq, rec_dir, rec_tr, rec_d2, d2max);
        density_merge_sym_kernel<<<N * 64 / 256, 256, 0, stream>>>(rec_dir, rec_tr, noise, density);
        parent_min_kernel<<<NPAIR, 256, 0, stream>>>(rec_d2, density, gmin);
    } else {
        // proven f64 fallback (GEMM recompute in symB)
        symA_f64_kernel<<<NPAIR, 256, 0, stream>>>(X, sq, rec_dir, rec_tr, d2max);
        density_merge_sym_kernel<<<N * 64 / 256, 256, 0, stream>>>(rec_dir, rec_tr, noise, density);
        symB_kernel<<<NPAIR, 256, 0, stream>>>(X, sq, density, gmin);
    }

    score_sym_kernel<<<N / 256, 256, 0, stream>>>(gmin, density, d2max, score);
    rank_kernel<<<N / 16, 256, 0, stream>>>(score, out);
}

// Round 8
// 243.419 us; speedup vs baseline: 1.0435x; 1.0113x over previous
//
#include <hip/hip_runtime.h>
#include <math.h>

#define N 8192
#define C 128
#define NC 256
#define KNN 5

#define TP 128                        // tile size
#define NTILE (N / TP)                // 64
#define NPAIR (NTILE * (NTILE + 1) / 2)   // 2080
#define CH 16                         // channels per staging chunk (f64 path)
#define PJ 130                        // LDS pitch over row-dim (f64 path)
#define SQRT_C 11.313708498984761     // sqrt(128)
#define RSTR (NTILE * KNN)            // 320 floats per row record

typedef double d4 __attribute__((ext_vector_type(4)));
using bf16x8 = __attribute__((ext_vector_type(8))) __bf16;
using f32x4  = __attribute__((ext_vector_type(4))) float;

static __device__ __forceinline__ unsigned rotl32(unsigned x, unsigned r) {
    return (x << r) | (x >> (32u - r));
}

// order-preserving double -> uint64 map (ascending)
static __device__ __forceinline__ unsigned long long dmap(double x) {
    long long b = __double_as_longlong(x);
    unsigned long long u = (unsigned long long)b;
    return (b >= 0) ? (u | 0x8000000000000000ull) : ~u;
}
static __device__ __forceinline__ double dunmap(unsigned long long u) {
    if (u & 0x8000000000000000ull) return __longlong_as_double((long long)(u ^ 0x8000000000000000ull));
    return __longlong_as_double((long long)(~u));
}

// async global->LDS, 16B per lane (dest = wave-uniform base + lane*16)
static __device__ __forceinline__ void gl_lds16(const void* g, void* l) {
    __builtin_amdgcn_global_load_lds(
        (const __attribute__((address_space(1))) void*)g,
        (__attribute__((address_space(3))) void*)l,
        16, 0, 0);
}

// ---------------------------------------------------------------------------
// Branchless sorted top-5 (ascending), f64 (fallback path).  (proven R13)
static __device__ __forceinline__ void ins5s(double (&m)[KNN], double v) {
    m[4] = fmin(m[4], fmax(m[3], v));
    m[3] = fmin(m[3], fmax(m[2], v));
    m[2] = fmin(m[2], fmax(m[1], v));
    m[1] = fmin(m[1], fmax(m[0], v));
    m[0] = fmin(m[0], v);
}
static __device__ __forceinline__ void sort5(double (&m)[KNN]) {
    double lo, hi;
#define CE(i, j) lo = fmin(m[i], m[j]); hi = fmax(m[i], m[j]); m[i] = lo; m[j] = hi;
    CE(0,1) CE(3,4) CE(2,4) CE(2,3) CE(0,3) CE(0,2) CE(1,4) CE(1,3) CE(1,2)
#undef CE
}
static __device__ __forceinline__ void bfly5s(double (&m)[KNN], int mask) {
    double pv[KNN];
    #pragma unroll
    for (int k = 0; k < KNN; k++) pv[k] = __shfl_xor(m[4 - k], mask, 64);
    #pragma unroll
    for (int k = 0; k < KNN; k++) m[k] = fmin(m[k], pv[k]);
    sort5(m);
}

// ---------------------------------------------------------------------------
// f32 versions (bf16 path).  Pure selection networks on f32 values: exact.
static __device__ __forceinline__ void ins5f(float (&m)[KNN], float v) {
    m[4] = fminf(m[4], fmaxf(m[3], v));
    m[3] = fminf(m[3], fmaxf(m[2], v));
    m[2] = fminf(m[2], fmaxf(m[1], v));
    m[1] = fminf(m[1], fmaxf(m[0], v));
    m[0] = fminf(m[0], v);
}
static __device__ __forceinline__ void sort5f(float (&m)[KNN]) {
    float lo, hi;
#define CE(i, j) lo = fminf(m[i], m[j]); hi = fmaxf(m[i], m[j]); m[i] = lo; m[j] = hi;
    CE(0,1) CE(3,4) CE(2,4) CE(2,3) CE(0,3) CE(0,2) CE(1,4) CE(1,3) CE(1,2)
#undef CE
}
static __device__ __forceinline__ void bfly5f(float (&m)[KNN], int mask) {
    float pv[KNN];
    #pragma unroll
    for (int k = 0; k < KNN; k++) pv[k] = __shfl_xor(m[4 - k], mask, 64);
    #pragma unroll
    for (int k = 0; k < KNN; k++) m[k] = fminf(m[k], pv[k]);
    sort5f(m);
}
static __device__ __forceinline__ void merge5f(float (&m)[KNN], const float* l) {
    #pragma unroll
    for (int k = 0; k < KNN; k++) m[k] = fminf(m[k], l[4 - k]);
    sort5f(m);
}

// ---------------------------------------------------------------------------
// f64 MFMA D-layout probe (proven R15) — fallback path only.
static __device__ __forceinline__ void probe_rows(int t, int r, int (&irow)[4]) {
    d4 pd = (d4){0.0, 0.0, 0.0, 0.0};
    pd = __builtin_amdgcn_mfma_f64_16x16x4f64((double)r, (r == 0) ? 1.0 : 0.0,
                                              pd, 0, 0, 0);
    #pragma unroll
    for (int j = 0; j < 4; j++) {
        double rv = __shfl(pd[j], t & 48, 64);   // group root lane 16*g
        irow[j] = (int)(rv * 0.25);
    }
}

// ---------------------------------------------------------------------------
// Fused setup: sq (f64 + f32) + gmin/d2max init + threefry noise + bf16x3
// plane split.  Planes channel-blocked: Xp[kg][point][8ch], kg = c>>3.
// ---------------------------------------------------------------------------
__global__ void setup_kernel(const float* __restrict__ X,
                             double* __restrict__ sq,
                             float* __restrict__ sqf,
                             unsigned long long* __restrict__ d2max,
                             unsigned long long* __restrict__ gmin,
                             float* __restrict__ noise,
                             __bf16* __restrict__ X1,
                             __bf16* __restrict__ X2,
                             __bf16* __restrict__ X3)
{
    int gid = blockIdx.x * blockDim.x + threadIdx.x;
    int wave = gid >> 6;
    int lane = threadIdx.x & 63;

    if (wave < N) {
        float f0 = X[wave * C + lane];
        float f1 = X[wave * C + 64 + lane];
        double v0 = (double)f0, v1 = (double)f1;
        double s = v0 * v0 + v1 * v1;
        #pragma unroll
        for (int off = 32; off > 0; off >>= 1) s += __shfl_down(s, off, 64);
        if (lane == 0) { sq[wave] = s; sqf[wave] = (float)s; }

        // split f32 -> 3 bf16 planes (RNE at each stage), blocked layout
        __bf16 a0 = (__bf16)f0; float r0 = f0 - (float)a0;
        __bf16 b0 = (__bf16)r0; r0 -= (float)b0;
        __bf16 c0 = (__bf16)r0;
        __bf16 a1 = (__bf16)f1; float r1 = f1 - (float)a1;
        __bf16 b1 = (__bf16)r1; r1 -= (float)b1;
        __bf16 c1 = (__bf16)r1;
        int cA = lane, cB = lane + 64;
        size_t iA = (size_t)(cA >> 3) * (N * 8) + (size_t)wave * 8 + (cA & 7);
        size_t iB = (size_t)(cB >> 3) * (N * 8) + (size_t)wave * 8 + (cB & 7);
        X1[iA] = a0;  X1[iB] = a1;
        X2[iA] = b0;  X2[iB] = b1;
        X3[iA] = c0;  X3[iB] = c1;
    }
    if (gid < N) gmin[gid] = 0xFFFFFFFFFFFFFFFFull;
    if (gid == 0) *d2max = 0ull;
    if (gid < N / 2) {
        int j = gid;
        const unsigned ks0 = 0u, ks1 = 1u;
        const unsigned ks2 = 0x1BD11BDAu ^ ks0 ^ ks1;
        unsigned x0 = (unsigned)j + ks0;
        unsigned x1 = (unsigned)(j + N / 2) + ks1;
        const unsigned rotA[4] = {13u, 15u, 26u, 6u};
        const unsigned rotB[4] = {17u, 29u, 16u, 24u};
        #pragma unroll
        for (int q = 0; q < 4; q++) { x0 += x1; x1 = rotl32(x1, rotA[q]); x1 ^= x0; }
        x0 += ks1; x1 += ks2 + 1u;
        #pragma unroll
        for (int q = 0; q < 4; q++) { x0 += x1; x1 = rotl32(x1, rotB[q]); x1 ^= x0; }
        x0 += ks2; x1 += ks0 + 2u;
        #pragma unroll
        for (int q = 0; q < 4; q++) { x0 += x1; x1 = rotl32(x1, rotA[q]); x1 ^= x0; }
        x0 += ks0; x1 += ks1 + 3u;
        #pragma unroll
        for (int q = 0; q < 4; q++) { x0 += x1; x1 = rotl32(x1, rotB[q]); x1 ^= x0; }
        x0 += ks1; x1 += ks2 + 4u;
        #pragma unroll
        for (int q = 0; q < 4; q++) { x0 += x1; x1 = rotl32(x1, rotA[q]); x1 ^= x0; }
        x0 += ks2; x1 += ks0 + 5u;
        unsigned b0u = (x0 >> 9) | 0x3f800000u;
        unsigned b1u = (x1 >> 9) | 0x3f800000u;
        noise[j]         = __uint_as_float(b0u) - 1.0f;
        noise[j + N / 2] = __uint_as_float(b1u) - 1.0f;
    }
}

// p = bj*(bj+1)/2 + bi, bi <= bj
static __device__ __forceinline__ void pair_decode(int p, int& bi, int& bj) {
    int b = (int)((sqrt(8.0 * (double)p + 1.0) - 1.0) * 0.5);
    while ((b + 1) * (b + 2) / 2 <= p) b++;
    while (b * (b + 1) / 2 > p) b--;
    bj = b;
    bi = p - b * (b + 1) / 2;
}

// ---------------------------------------------------------------------------
// symA_bf16: bf16x3 split-GEMM via v_mfma_f32_16x16x32_bf16.
//  - staging as R7 (coalesced, gl_lds16 dbuf B, pipelined A).  acc bit-identical.
//  - epilogue in f32 (sqf): v = sqa+sqj-2*acc, f32 top-5 (exact selection).
//  - records: unified rec[row][64][5]; rows-part -> rec[i0+row][bj],
//    cols-part -> rec[j0+col][bi]  (one writer per slot incl. diagonal).
//  - d2 tile store moved to kernel END (drains at kernel exit, not at barrier).
// ---------------------------------------------------------------------------
__launch_bounds__(256, 2)
__global__ void symA_bf16_kernel(const __bf16* __restrict__ X1,
                                 const __bf16* __restrict__ X2,
                                 const __bf16* __restrict__ X3,
                                 const float* __restrict__ sqf,
                                 float* __restrict__ rec,
                                 float* __restrict__ rec_d2,
                                 unsigned long long* __restrict__ d2max_p)
{
    __shared__ __align__(16) float4 Sb[2 * 1536];   // 49,152 B (double-buffered B)

    const int t = threadIdx.x;
    const int r = t & 15;
    const int g = (t >> 4) & 3;
    const int w = t >> 6;
    const int l = t & 63;
    const int w32 = w * 32;
    int bi, bj;
    pair_decode(blockIdx.x, bi, bj);
    const int i0 = bi * TP, j0 = bj * TP;

    f32x4 acc[2][8];
    #pragma unroll
    for (int mt = 0; mt < 2; mt++)
        #pragma unroll
        for (int nt = 0; nt < 8; nt++) acc[mt][nt] = (f32x4){0.f, 0.f, 0.f, 0.f};

    const int kgw = (w >> 1);
    const int p0  = (w & 1) * 64;

#define STAGE_B(ck, buf)                                                       \
    {                                                                          \
        _Pragma("unroll")                                                      \
        for (int pl = 0; pl < 3; pl++) {                                       \
            const __bf16* P = (pl == 0) ? X1 : ((pl == 1) ? X2 : X3);          \
            _Pragma("unroll")                                                  \
            for (int h = 0; h < 2; h++) {                                      \
                int kg = (ck) * 4 + h * 2 + kgw;                               \
                const __bf16* gp = P + (size_t)kg * (N * 8)                    \
                                     + (size_t)(j0 + p0 + l) * 8;              \
                float4* lp = Sb + (buf) * 1536 + pl * 512 + h * 256 + w * 64;  \
                gl_lds16((const void*)gp, (void*)lp);                          \
            }                                                                  \
        }                                                                      \
    }

#define LOAD_A(ck, areg)                                                       \
    {                                                                          \
        size_t kga = (size_t)((ck) * 4 + g) * (N * 8);                         \
        size_t a0o = kga + (size_t)(i0 + w32 + r) * 8;                         \
        size_t a1o = kga + (size_t)(i0 + w32 + 16 + r) * 8;                    \
        areg[0][0] = *(const bf16x8*)(X1 + a0o);                               \
        areg[0][1] = *(const bf16x8*)(X2 + a0o);                               \
        areg[0][2] = *(const bf16x8*)(X3 + a0o);                               \
        areg[1][0] = *(const bf16x8*)(X1 + a1o);                               \
        areg[1][1] = *(const bf16x8*)(X2 + a1o);                               \
        areg[1][2] = *(const bf16x8*)(X3 + a1o);                               \
    }

    bf16x8 areg[2][2][3];   // [parity][mt][pl] — static-indexed after unroll

    // prologue: A(0) + stage B(0) into buffer 0
    LOAD_A(0, areg[0])
    STAGE_B(0, 0)
    __syncthreads();

    #pragma unroll
    for (int ck = 0; ck < 4; ck++) {
        const int cur = ck & 1;
        if (ck < 3) {
            STAGE_B(ck + 1, cur ^ 1)      // async global->LDS (next B)
            LOAD_A(ck + 1, areg[cur ^ 1]) // global->VGPR (next A, drains at barrier)
        }
        const bf16x8* SB = (const bf16x8*)Sb + (size_t)cur * 1536;
        #pragma unroll
        for (int nt = 0; nt < 8; nt++) {
            bf16x8 b0 = SB[0 * 512 + g * 128 + nt * 16 + r];
            bf16x8 b1 = SB[1 * 512 + g * 128 + nt * 16 + r];
            bf16x8 b2 = SB[2 * 512 + g * 128 + nt * 16 + r];
            #pragma unroll
            for (int mt = 0; mt < 2; mt++) {
                f32x4 c = acc[mt][nt];
                c = __builtin_amdgcn_mfma_f32_16x16x32_bf16(areg[cur][mt][0], b0, c, 0, 0, 0);
                c = __builtin_amdgcn_mfma_f32_16x16x32_bf16(areg[cur][mt][0], b1, c, 0, 0, 0);
                c = __builtin_amdgcn_mfma_f32_16x16x32_bf16(areg[cur][mt][1], b0, c, 0, 0, 0);
                c = __builtin_amdgcn_mfma_f32_16x16x32_bf16(areg[cur][mt][0], b2, c, 0, 0, 0);
                c = __builtin_amdgcn_mfma_f32_16x16x32_bf16(areg[cur][mt][2], b0, c, 0, 0, 0);
                c = __builtin_amdgcn_mfma_f32_16x16x32_bf16(areg[cur][mt][1], b1, c, 0, 0, 0);
                acc[mt][nt] = c;
            }
        }
        __syncthreads();   // drains vmcnt -> next buffer + next A ready
    }
#undef STAGE_B
#undef LOAD_A

    // d2 in place — all f32 (sqf): v = sqa + sqj - 2*acc
    float sqa[2][4], sqj[8];
    #pragma unroll
    for (int mt = 0; mt < 2; mt++)
        #pragma unroll
        for (int j = 0; j < 4; j++) sqa[mt][j] = sqf[i0 + w32 + mt * 16 + g * 4 + j];
    #pragma unroll
    for (int nt = 0; nt < 8; nt++) sqj[nt] = sqf[j0 + nt * 16 + r];
    float rmax = 0.0f;
    #pragma unroll
    for (int mt = 0; mt < 2; mt++)
        #pragma unroll
        for (int nt = 0; nt < 8; nt++)
            #pragma unroll
            for (int j = 0; j < 4; j++) {
                float v = fmaf(-2.0f, acc[mt][nt][j], sqa[mt][j] + sqj[nt]);
                acc[mt][nt][j] = v;
                rmax = fmaxf(rmax, v);
            }
    #pragma unroll
    for (int off = 32; off > 0; off >>= 1) rmax = fmaxf(rmax, __shfl_down(rmax, off, 64));
    if ((t & 63) == 0)
        atomicMax(d2max_p, (unsigned long long)__double_as_longlong(fmax((double)rmax, 0.0)));

    // ---- rows: lane scans 8 nt values; bfly over r lanes; r==0 writes.
    #pragma unroll
    for (int mt = 0; mt < 2; mt++)
        #pragma unroll
        for (int j = 0; j < 4; j++) {
            float m5[KNN];
            #pragma unroll
            for (int k = 0; k < KNN; k++) m5[k] = 3.0e38f;
            #pragma unroll
            for (int nt = 0; nt < 8; nt++) ins5f(m5, acc[mt][nt][j]);
            bfly5f(m5, 1); bfly5f(m5, 2); bfly5f(m5, 4); bfly5f(m5, 8);
            if (r == 0) {
                int row = w32 + mt * 16 + g * 4 + j;
                float* outp = &rec[(size_t)(i0 + row) * RSTR + bj * KNN];
                #pragma unroll
                for (int k = 0; k < KNN; k++) outp[k] = m5[k];
            }
        }

    // ---- cols (off-diagonal): scan 8 (mt,j); bfly over g (16,32); LDS merge
    if (bi != bj) {
        float* M = (float*)Sb;   // [col][21] : 4 wave-partials x 5
        #pragma unroll
        for (int nt = 0; nt < 8; nt++) {
            float m5[KNN];
            #pragma unroll
            for (int k = 0; k < KNN; k++) m5[k] = 3.0e38f;
            #pragma unroll
            for (int mt = 0; mt < 2; mt++)
                #pragma unroll
                for (int j = 0; j < 4; j++) ins5f(m5, acc[mt][nt][j]);
            bfly5f(m5, 16); bfly5f(m5, 32);
            if (g == 0) {
                int col = nt * 16 + r;
                #pragma unroll
                for (int k = 0; k < KNN; k++) M[col * 21 + w * 5 + k] = m5[k];
            }
        }
        __syncthreads();
        if (t < 128) {
            float m5[KNN];
            #pragma unroll
            for (int k = 0; k < KNN; k++) m5[k] = M[t * 21 + k];
            merge5f(m5, &M[t * 21 + 5]);
            merge5f(m5, &M[t * 21 + 10]);
            merge5f(m5, &M[t * 21 + 15]);
            float* outp = &rec[(size_t)(j0 + t) * RSTR + bi * KNN];
            #pragma unroll
            for (int k = 0; k < KNN; k++) outp[k] = m5[k];
        }
    }

    // ---- PERMUTED d2 store LAST: no barrier follows -> drains at kernel end.
    {
        float4* outp = (float4*)(rec_d2 + (size_t)blockIdx.x * (TP * TP));
        #pragma unroll
        for (int mt = 0; mt < 2; mt++)
            #pragma unroll
            for (int nt = 0; nt < 8; nt++) {
                f32x4 v = acc[mt][nt];
                outp[(mt * 8 + nt) * 256 + t] = (float4){v[0], v[1], v[2], v[3]};
            }
    }
}

// ---------------------------------------------------------------------------
// f64 MFMA GEMM body (proven) — fallback path only.
// ---------------------------------------------------------------------------
#define MFMA_GEMM_BODY(acc, As, Bs, X4, i0, j0, t, r, g, w32)                  \
    {                                                                          \
        float4 pa[2], pb[2];                                                   \
        _Pragma("unroll")                                                      \
        for (int q = 0; q < 2; q++) {                                          \
            int flat = t + 256 * q;                                            \
            int row = flat >> 2, c4 = flat & 3;                                \
            pa[q] = X4[(size_t)(i0 + row) * 32 + c4];                          \
            pb[q] = X4[(size_t)(j0 + row) * 32 + c4];                          \
        }                                                                      \
        for (int ck = 0; ck < 8; ck++) {                                       \
            _Pragma("unroll")                                                  \
            for (int q = 0; q < 2; q++) {                                      \
                int flat = t + 256 * q;                                        \
                int row = flat >> 2, c4 = flat & 3;                            \
                As[(4 * c4 + 0) * PJ + row] = (double)pa[q].x;                 \
                As[(4 * c4 + 1) * PJ + row] = (double)pa[q].y;                 \
                As[(4 * c4 + 2) * PJ + row] = (double)pa[q].z;                 \
                As[(4 * c4 + 3) * PJ + row] = (double)pa[q].w;                 \
                Bs[(4 * c4 + 0) * PJ + row] = (double)pb[q].x;                 \
                Bs[(4 * c4 + 1) * PJ + row] = (double)pb[q].y;                 \
                Bs[(4 * c4 + 2) * PJ + row] = (double)pb[q].z;                 \
                Bs[(4 * c4 + 3) * PJ + row] = (double)pb[q].w;                 \
            }                                                                  \
            __syncthreads();                                                   \
            if (ck < 7) {                                                      \
                _Pragma("unroll")                                              \
                for (int q = 0; q < 2; q++) {                                  \
                    int flat = t + 256 * q;                                    \
                    int row = flat >> 2, c4 = flat & 3;                        \
                    pa[q] = X4[(size_t)(i0 + row) * 32 + (ck + 1) * 4 + c4];   \
                    pb[q] = X4[(size_t)(j0 + row) * 32 + (ck + 1) * 4 + c4];   \
                }                                                              \
            }                                                                  \
            _Pragma("unroll")                                                  \
            for (int ks = 0; ks < 4; ks++) {                                   \
                int cc = 4 * ks + g;                                           \
                double a0 = As[cc * PJ + w32 + r];                             \
                double a1 = As[cc * PJ + w32 + 16 + r];                        \
                double bv[8];                                                  \
                _Pragma("unroll")                                              \
                for (int nt = 0; nt < 8; nt++) bv[nt] = Bs[cc * PJ + nt * 16 + r]; \
                _Pragma("unroll")                                              \
                for (int nt = 0; nt < 8; nt++)                                 \
                    acc[0][nt] = __builtin_amdgcn_mfma_f64_16x16x4f64(a0, bv[nt], acc[0][nt], 0, 0, 0); \
                _Pragma("unroll")                                              \
                for (int nt = 0; nt < 8; nt++)                                 \
                    acc[1][nt] = __builtin_amdgcn_mfma_f64_16x16x4f64(a1, bv[nt], acc[1][nt], 0, 0, 0); \
            }                                                                  \
            __syncthreads();                                                   \
        }                                                                      \
    }

// ---------------------------------------------------------------------------
// symA_f64 (fallback): proven f64 GEMM + top-5 epilogue, unified records.
// ---------------------------------------------------------------------------
__launch_bounds__(256, 2)
__global__ void symA_f64_kernel(const float* __restrict__ X,
                                const double* __restrict__ sq,
                                float* __restrict__ rec,
                                unsigned long long* __restrict__ d2max_p)
{
    __shared__ __align__(16) double S[2 * CH * PJ];
    double* As = S;
    double* Bs = S + CH * PJ;

    const int t = threadIdx.x;
    const int r = t & 15;
    const int g = (t >> 4) & 3;
    const int w = t >> 6;
    const int w32 = w * 32;
    int bi, bj;
    pair_decode(blockIdx.x, bi, bj);
    const int i0 = bi * TP, j0 = bj * TP;
    const float4* X4 = (const float4*)X;

    int irow[4];
    probe_rows(t, r, irow);

    d4 acc[2][8];
    #pragma unroll
    for (int mt = 0; mt < 2; mt++)
        #pragma unroll
        for (int nt = 0; nt < 8; nt++) acc[mt][nt] = (d4){0.0, 0.0, 0.0, 0.0};

    MFMA_GEMM_BODY(acc, As, Bs, X4, i0, j0, t, r, g, w32)

    double sqa[2][4], sqj[8];
    #pragma unroll
    for (int mt = 0; mt < 2; mt++)
        #pragma unroll
        for (int j = 0; j < 4; j++) sqa[mt][j] = sq[i0 + w32 + mt * 16 + irow[j]];
    #pragma unroll
    for (int nt = 0; nt < 8; nt++) sqj[nt] = sq[j0 + nt * 16 + r];
    double rmax = 0.0;
    #pragma unroll
    for (int mt = 0; mt < 2; mt++)
        #pragma unroll
        for (int nt = 0; nt < 8; nt++)
            #pragma unroll
            for (int j = 0; j < 4; j++) {
                double v = sqa[mt][j] + sqj[nt] - 2.0 * acc[mt][nt][j];
                acc[mt][nt][j] = v;
                rmax = fmax(rmax, v);
            }
    #pragma unroll
    for (int off = 32; off > 0; off >>= 1) rmax = fmax(rmax, __shfl_down(rmax, off, 64));
    if ((t & 63) == 0)
        atomicMax(d2max_p, (unsigned long long)__double_as_longlong(fmax(rmax, 0.0)));

    #pragma unroll
    for (int mt = 0; mt < 2; mt++)
        #pragma unroll
        for (int j = 0; j < 4; j++) {
            double m5[KNN];
            #pragma unroll
            for (int k = 0; k < KNN; k++) m5[k] = 1e300;
            #pragma unroll
            for (int nt = 0; nt < 8; nt++) ins5s(m5, acc[mt][nt][j]);
            bfly5s(m5, 1); bfly5s(m5, 2); bfly5s(m5, 4); bfly5s(m5, 8);
            if (r == 0) {
                int row = w32 + mt * 16 + irow[j];
                float* outp = &rec[(size_t)(i0 + row) * RSTR + bj * KNN];
                #pragma unroll
                for (int k = 0; k < KNN; k++) outp[k] = (float)m5[k];
            }
        }

    if (bi != bj) {
        double* M = S;
        #pragma unroll
        for (int nt = 0; nt < 8; nt++) {
            double m5[KNN];
            #pragma unroll
            for (int k = 0; k < KNN; k++) m5[k] = 1e300;
            #pragma unroll
            for (int mt = 0; mt < 2; mt++)
                #pragma unroll
                for (int j = 0; j < 4; j++) ins5s(m5, acc[mt][nt][j]);
            bfly5s(m5, 16); bfly5s(m5, 32);
            if (g == 0) {
                int col = nt * 16 + r;
                #pragma unroll
                for (int k = 0; k < KNN; k++) M[col * 21 + w * 5 + k] = m5[k];
            }
        }
        __syncthreads();
        if (t < 128) {
            float m5[KNN];
            #pragma unroll
            for (int k = 0; k < KNN; k++) m5[k] = (float)M[t * 21 + k];
            float o5[KNN];
            #pragma unroll
            for (int k = 0; k < KNN; k++) o5[k] = (float)M[t * 21 + 5 + k];
            merge5f(m5, o5);
            #pragma unroll
            for (int k = 0; k < KNN; k++) o5[k] = (float)M[t * 21 + 10 + k];
            merge5f(m5, o5);
            #pragma unroll
            for (int k = 0; k < KNN; k++) o5[k] = (float)M[t * 21 + 15 + k];
            merge5f(m5, o5);
            float* outp = &rec[(size_t)(j0 + t) * RSTR + bi * KNN];
            #pragma unroll
            for (int k = 0; k < KNN; k++) outp[k] = m5[k];
        }
    }
}

// ---------------------------------------------------------------------------
// Merge records -> density.  One WAVE per row; lane l reads its 20B slot of
// the row's contiguous 1280B record block (fully coalesced), 6 bfly stages.
// ---------------------------------------------------------------------------
__global__ void density_merge_sym_kernel(const float* __restrict__ rec,
                                         const float* __restrict__ noise,
                                         double* __restrict__ density)
{
    int i = (blockIdx.x * blockDim.x + threadIdx.x) >> 6;   // row = global wave
    int l = threadIdx.x & 63;
    if (i >= N) return;
    float m5[KNN];
    const float* rp = &rec[(size_t)i * RSTR + l * KNN];
    #pragma unroll
    for (int k = 0; k < KNN; k++) m5[k] = rp[k];
    bfly5f(m5, 1); bfly5f(m5, 2); bfly5f(m5, 4);
    bfly5f(m5, 8); bfly5f(m5, 16); bfly5f(m5, 32);
    if (l == 0) {
        double s2 = 0.0;
        #pragma unroll
        for (int k = 0; k < KNN; k++) {
            double z = m5[k] > 0.0f ? (double)m5[k] : 0.0;
            double d = sqrt(z) / SQRT_C;
            s2 += d * d;
        }
        density[i] = exp(-s2 / 5.0) + (double)(noise[i] * 1e-6f);
    }
}

// ---------------------------------------------------------------------------
// parent_min: coalesced float4 loads of the PERMUTED d2 tiles, then the
// proven symB masked-min epilogue (density compares in f64, mins in f32).
// ---------------------------------------------------------------------------
__launch_bounds__(256)
__global__ void parent_min_kernel(const float* __restrict__ rec_d2,
                                  const double* __restrict__ density,
                                  unsigned long long* __restrict__ gmin)
{
    int bi, bj;
    pair_decode(blockIdx.x, bi, bj);
    const int i0 = bi * TP, j0 = bj * TP;
    const int t = threadIdx.x;
    const int r = t & 15;
    const int g = (t >> 4) & 3;
    const int w = t >> 6;
    const int w32 = w * 32;
    const float4* tile = (const float4*)(rec_d2 + (size_t)blockIdx.x * (TP * TP));

    float4 acc[2][8];
    #pragma unroll
    for (int mt = 0; mt < 2; mt++)
        #pragma unroll
        for (int nt = 0; nt < 8; nt++)
            acc[mt][nt] = tile[(mt * 8 + nt) * 256 + t];

    double di[2][4], dj[8];
    float dmr[2][4], dmc[8];
    #pragma unroll
    for (int mt = 0; mt < 2; mt++)
        #pragma unroll
        for (int j = 0; j < 4; j++) {
            di[mt][j] = density[i0 + w32 + mt * 16 + g * 4 + j];
            dmr[mt][j] = 3.0e38f;
        }
    #pragma unroll
    for (int nt = 0; nt < 8; nt++) {
        dj[nt] = density[j0 + nt * 16 + r];
        dmc[nt] = 3.0e38f;
    }

    #pragma unroll
    for (int mt = 0; mt < 2; mt++)
        #pragma unroll
        for (int nt = 0; nt < 8; nt++) {
            float4 v4 = acc[mt][nt];
            float vv[4] = {v4.x, v4.y, v4.z, v4.w};
            #pragma unroll
            for (int j = 0; j < 4; j++) {
                float v = vv[j];
                if (dj[nt] > di[mt][j]) dmr[mt][j] = fminf(dmr[mt][j], v);
                if (di[mt][j] > dj[nt]) dmc[nt] = fminf(dmc[nt], v);
            }
        }

    // rows: butterfly over r lanes; r==0 atomicMin
    #pragma unroll
    for (int mt = 0; mt < 2; mt++)
        #pragma unroll
        for (int j = 0; j < 4; j++) {
            #pragma unroll
            for (int m = 1; m <= 8; m <<= 1)
                dmr[mt][j] = fminf(dmr[mt][j], __shfl_xor(dmr[mt][j], m, 64));
        }
    if (r == 0) {
        #pragma unroll
        for (int mt = 0; mt < 2; mt++)
            #pragma unroll
            for (int j = 0; j < 4; j++)
                if (dmr[mt][j] < 1.0e38f) {
                    int row = w32 + mt * 16 + g * 4 + j;
                    atomicMin(&gmin[i0 + row], dmap((double)dmr[mt][j]));
                }
    }
    // cols: butterfly over g (16,32); g==0 atomicMin
    if (bi != bj) {
        #pragma unroll
        for (int nt = 0; nt < 8; nt++) {
            #pragma unroll
            for (int m = 16; m <= 32; m <<= 1)
                dmc[nt] = fminf(dmc[nt], __shfl_xor(dmc[nt], m, 64));
        }
        if (g == 0) {
            #pragma unroll
            for (int nt = 0; nt < 8; nt++)
                if (dmc[nt] < 1.0e38f) {
                    int col = nt * 16 + r;
                    atomicMin(&gmin[j0 + col], dmap((double)dmc[nt]));
                }
        }
    }
}

// ---------------------------------------------------------------------------
// symB (fallback): f64 GEMM recompute + masked row/col mins.  (proven)
// ---------------------------------------------------------------------------
__launch_bounds__(256, 2)
__global__ void symB_kernel(const float* __restrict__ X,
                            const double* __restrict__ sq,
                            const double* __restrict__ density,
                            unsigned long long* __restrict__ gmin)
{
    __shared__ __align__(16) double S[2 * CH * PJ];
    double* As = S;
    double* Bs = S + CH * PJ;

    const int t = threadIdx.x;
    const int r = t & 15;
    const int g = (t >> 4) & 3;
    const int w = t >> 6;
    const int w32 = w * 32;
    int bi, bj;
    pair_decode(blockIdx.x, bi, bj);
    const int i0 = bi * TP, j0 = bj * TP;
    const float4* X4 = (const float4*)X;

    int irow[4];
    probe_rows(t, r, irow);

    d4 acc[2][8];
    #pragma unroll
    for (int mt = 0; mt < 2; mt++)
        #pragma unroll
        for (int nt = 0; nt < 8; nt++) acc[mt][nt] = (d4){0.0, 0.0, 0.0, 0.0};

    MFMA_GEMM_BODY(acc, As, Bs, X4, i0, j0, t, r, g, w32)

    double sqa[2][4], di[2][4], sqj[8], dj[8], dmr[2][4], dmc[8];
    #pragma unroll
    for (int mt = 0; mt < 2; mt++)
        #pragma unroll
        for (int j = 0; j < 4; j++) {
            int row = w32 + mt * 16 + irow[j];
            sqa[mt][j] = sq[i0 + row];
            di[mt][j] = density[i0 + row];
            dmr[mt][j] = 1e300;
        }
    #pragma unroll
    for (int nt = 0; nt < 8; nt++) {
        int col = nt * 16 + r;
        sqj[nt] = sq[j0 + col];
        dj[nt] = density[j0 + col];
        dmc[nt] = 1e300;
    }

    #pragma unroll
    for (int mt = 0; mt < 2; mt++)
        #pragma unroll
        for (int nt = 0; nt < 8; nt++)
            #pragma unroll
            for (int j = 0; j < 4; j++) {
                double v = sqa[mt][j] + sqj[nt] - 2.0 * acc[mt][nt][j];
                if (dj[nt] > di[mt][j]) dmr[mt][j] = fmin(dmr[mt][j], v);
                if (di[mt][j] > dj[nt]) dmc[nt] = fmin(dmc[nt], v);
            }

    #pragma unroll
    for (int mt = 0; mt < 2; mt++)
        #pragma unroll
        for (int j = 0; j < 4; j++) {
            #pragma unroll
            for (int m = 1; m <= 8; m <<= 1)
                dmr[mt][j] = fmin(dmr[mt][j], __shfl_xor(dmr[mt][j], m, 64));
        }
    if (r == 0) {
        #pragma unroll
        for (int mt = 0; mt < 2; mt++)
            #pragma unroll
            for (int j = 0; j < 4; j++)
                if (dmr[mt][j] < 9.9e299) {
                    int row = w32 + mt * 16 + irow[j];
                    atomicMin(&gmin[i0 + row], dmap(dmr[mt][j]));
                }
    }
    if (bi != bj) {
        #pragma unroll
        for (int nt = 0; nt < 8; nt++) {
            #pragma unroll
            for (int m = 16; m <= 32; m <<= 1)
                dmc[nt] = fmin(dmc[nt], __shfl_xor(dmc[nt], m, 64));
        }
        if (g == 0) {
            #pragma unroll
            for (int nt = 0; nt < 8; nt++)
                if (dmc[nt] < 9.9e299) {
                    int col = nt * 16 + r;
                    atomicMin(&gmin[j0 + col], dmap(dmc[nt]));
                }
        }
    }
}

// ---------------------------------------------------------------------------
__global__ void score_sym_kernel(const unsigned long long* __restrict__ gmin,
                                 const double* __restrict__ density,
                                 const unsigned long long* __restrict__ d2max_p,
                                 double* __restrict__ score)
{
    int i = blockIdx.x * blockDim.x + threadIdx.x;
    if (i >= N) return;
    unsigned long long u = gmin[i];
    double d2m = __longlong_as_double((long long)(*d2max_p));
    double distmax = sqrt(fmax(d2m, 0.0)) / SQRT_C;
    double dp;
    if (u == 0xFFFFFFFFFFFFFFFFull) {
        dp = distmax;
    } else {
        double dmin = dunmap(u);
        dp = sqrt(fmax(dmin, 0.0)) / SQRT_C;
    }
    score[i] = dp * density[i];
}

// ---------------------------------------------------------------------------
// Stable descending rank; 512 blocks, 16-way j-split per row, shuffle reduce.
// ---------------------------------------------------------------------------
__launch_bounds__(256)
__global__ void rank_kernel(const double* __restrict__ score, int* __restrict__ out)
{
    __shared__ double Ss[N];   // 64 KB
    for (int k = 0; k < N / 256; k++) {
        int idx = threadIdx.x + 256 * k;
        Ss[idx] = score[idx];
    }
    __syncthreads();
    int il = threadIdx.x >> 4;          // 0..15
    int ch = threadIdx.x & 15;          // 0..15
    int i = blockIdx.x * 16 + il;
    double si = Ss[i];
    int cnt = 0;
    for (int q = 0; q < N / 16; q++) {
        int j = ch + (q << 4);
        double sj = Ss[j];
        cnt += (sj > si) || (sj == si && j < i);
    }
    cnt += __shfl_down(cnt, 8, 16);
    cnt += __shfl_down(cnt, 4, 16);
    cnt += __shfl_down(cnt, 2, 16);
    cnt += __shfl_down(cnt, 1, 16);
    if (ch == 0 && cnt < NC) out[cnt] = i;
}

// ---------------------------------------------------------------------------
extern "C" void kernel_launch(void* const* d_in, const int* in_sizes, int n_in,
                              void* d_out, int out_size, void* d_ws, size_t ws_size,
                              hipStream_t stream) {
    const float* X = (const float*)d_in[0];
    int* out = (int*)d_out;

    double* ws      = (double*)d_ws;
    double* sq      = ws;                      // 8192 f64
    double* density = ws + 8192;               // 8192 f64
    double* score   = ws + 16384;              // 8192 f64
    unsigned long long* d2max = (unsigned long long*)(ws + 24576);
    unsigned long long* gmin  = (unsigned long long*)(ws + 24584);  // 8192
    float*  noise   = (float*)(ws + 32776);    // 8192 f32
    float*  sqf     = (float*)(ws + 36872);    // 8192 f32  (ends ~311 KB)

    // bf16 planes at 1/3/5 MB (2 MB each), channel-blocked [kg][point][8]
    __bf16* X1 = (__bf16*)((char*)d_ws + (1ull << 20));
    __bf16* X2 = (__bf16*)((char*)d_ws + (3ull << 20));
    __bf16* X3 = (__bf16*)((char*)d_ws + (5ull << 20));

    // unified f32 records rec[row][64][5] + f32 d2 tiles from 8 MB
    const size_t REC_OFF    = 8ull << 20;
    const size_t rec_elems  = (size_t)N * RSTR;           // 2,621,440
    const size_t tile_elems = (size_t)NPAIR * TP * TP;    // 34,078,720
    float* rec    = (float*)((char*)d_ws + REC_OFF);
    float* rec_d2 = rec + rec_elems;
    const size_t need = REC_OFF + (rec_elems + tile_elems) * sizeof(float);  // ~155 MB

    setup_kernel<<<N / 4, 256, 0, stream>>>(X, sq, sqf, d2max, gmin, noise, X1, X2, X3);

    if (ws_size >= need) {
        // bf16x3 split-GEMM path (f32 d2, stored tiles, no recompute)
        symA_bf16_kernel<<<NPAIR, 256, 0, stream>>>(X1, X2, X3, sqf, rec, rec_d2, d2max);
        density_merge_sym_kernel<<<N * 64 / 256, 256, 0, stream>>>(rec, noise, density);
        parent_min_kernel<<<NPAIR, 256, 0, stream>>>(rec_d2, density, gmin);
    } else {
        // proven f64 fallback (GEMM recompute in symB)
        symA_f64_kernel<<<NPAIR, 256, 0, stream>>>(X, sq, rec, d2max);
        density_merge_sym_kernel<<<N * 64 / 256, 256, 0, stream>>>(rec, noise, density);
        symB_kernel<<<NPAIR, 256, 0, stream>>>(X, sq, density, gmin);
    }

    score_sym_kernel<<<N / 256, 256, 0, stream>>>(gmin, density, d2max, score);
    rank_kernel<<<N / 16, 256, 0, stream>>>(score, out);
}